// Round 1
// baseline (677.009 us; speedup 1.0000x reference)
//
#include <hip/hip_runtime.h>
#include <hip/hip_bf16.h>

// Qwen3.5 GatedDeltaNet forward, chunked delta-rule formulation.
// B=2,T=2048,D=1024, HV=16,HK=8,DK=DV=64, chunk=64 (32 chunks).

typedef unsigned short u16;
typedef float f32x4 __attribute__((ext_vector_type(4)));
typedef short bf16x8 __attribute__((ext_vector_type(8)));
typedef u16 u16x4 __attribute__((ext_vector_type(4)));
typedef const __attribute__((address_space(1))) void* gptr_t;
typedef __attribute__((address_space(3))) void* lptr_t;

#define B_    2
#define T_    2048
#define HV_   16
#define HK_   8
#define NC_   32      // chunks
#define BT_   4096
#define QKVZ_ 3072
#define NCOL_ 3200    // gemm1 padded N (2048 qkv + 1024 z + 128 beta/a pad)

__device__ __forceinline__ u16 f2bf(float f) {
  return __builtin_bit_cast(u16, __float2bfloat16(f));
}
__device__ __forceinline__ float bf2f(u16 u) {
  return __bfloat162float(__builtin_bit_cast(__hip_bfloat16, u));
}
__device__ __forceinline__ float sigm(float x) { return 1.f / (1.f + __expf(-x)); }

// ---------------- cast hs -> bf16 ----------------
__global__ __launch_bounds__(256) void k_cast_hs(const float* __restrict__ in,
                                                 u16* __restrict__ out) {
  int i = (blockIdx.x * 256 + threadIdx.x) * 4;
  float4 v = *(const float4*)(in + i);
  u16x4 o; o.x = f2bf(v.x); o.y = f2bf(v.y); o.z = f2bf(v.z); o.w = f2bf(v.w);
  *(u16x4*)(out + i) = o;
}

// ---------------- generic transpose+cast: dst[c][r] = src[r][c] ----------------
__global__ __launch_bounds__(256) void k_tcast(const float* __restrict__ src,
                                               u16* __restrict__ dst, int R, int C) {
  __shared__ float tile[32][33];
  int c0 = blockIdx.x * 32, r0 = blockIdx.y * 32;
  int cx = threadIdx.x & 31, ry = threadIdx.x >> 5;
#pragma unroll
  for (int j = 0; j < 4; ++j)
    tile[ry * 4 + j][cx] = src[(long)(r0 + ry * 4 + j) * C + c0 + cx];
  __syncthreads();
#pragma unroll
  for (int j = 0; j < 4; ++j)
    dst[(long)(c0 + ry * 4 + j) * R + r0 + cx] = f2bf(tile[cx][ry * 4 + j]);
}

// ---------------- build Wcat^T [3200][1024] from W_qkv|W_z|W_b|W_a ----------------
__global__ __launch_bounds__(256) void k_wcatT(const float* __restrict__ Wqkv,
                                               const float* __restrict__ Wz,
                                               const float* __restrict__ Wb,
                                               const float* __restrict__ Wa,
                                               u16* __restrict__ dst) {
  __shared__ float tile[32][33];
  int n0 = blockIdx.x * 32, k0 = blockIdx.y * 32;
  int cx = threadIdx.x & 31, ry = threadIdx.x >> 5;
#pragma unroll
  for (int j = 0; j < 4; ++j) {
    int kk = k0 + ry * 4 + j;
    int n = n0 + cx;
    float v;
    if (n < 2048)      v = Wqkv[(long)kk * 2048 + n];
    else if (n < 3072) v = Wz[(long)kk * 1024 + (n - 2048)];
    else if (n < 3088) v = Wb[kk * 16 + (n - 3072)];
    else if (n < 3104) v = Wa[kk * 16 + (n - 3088)];
    else               v = 0.f;
    tile[ry * 4 + j][cx] = v;
  }
  __syncthreads();
#pragma unroll
  for (int j = 0; j < 4; ++j)
    dst[(long)(n0 + ry * 4 + j) * 1024 + k0 + cx] = f2bf(tile[cx][ry * 4 + j]);
}

// ---------------- bf16 MFMA GEMM: C[M,N] = A[M,K] @ Bt[N,K]^T ----------------
// 128x128 tile, BK=64, 4 waves, global_load_lds width-16 (m97 structure).
// mode 0: col<3072 -> bf16 C0 (stride 3072), col>=3072 -> f32 C1 (stride 128)
// mode 1: f32 C1 stride N
__global__ __launch_bounds__(256) void k_gemm(const u16* __restrict__ A,
                                              const u16* __restrict__ Bt,
                                              u16* __restrict__ C0,
                                              float* __restrict__ C1,
                                              int M, int N, int K, int mode) {
  __shared__ u16 As[128 * 64];
  __shared__ u16 Bs[128 * 64];
  int tid = threadIdx.x;
  int wid = tid >> 6, lane = tid & 63;
  int row0 = blockIdx.y * 128, col0 = blockIdx.x * 128;
  int wr = wid >> 1, wc = wid & 1;
  f32x4 acc[4][4];
#pragma unroll
  for (int m = 0; m < 4; ++m)
#pragma unroll
    for (int n = 0; n < 4; ++n) acc[m][n] = (f32x4){0.f, 0.f, 0.f, 0.f};

  int srow = lane >> 3;          // 0..7 (row within 8-row segment)
  int skoff = (lane & 7) * 8;    // k element offset (16B per lane)

  for (int k0 = 0; k0 < K; k0 += 64) {
#pragma unroll
    for (int it = 0; it < 4; ++it) {
      int seg = wid * 4 + it;                 // 16 segments of 1024B each
      int r = seg * 8 + srow;
      const u16* gA = A + (long)(row0 + r) * K + k0 + skoff;
      const u16* gB = Bt + (long)(col0 + r) * K + k0 + skoff;
      __builtin_amdgcn_global_load_lds((gptr_t)gA, (lptr_t)(As + seg * 512), 16, 0, 0);
      __builtin_amdgcn_global_load_lds((gptr_t)gB, (lptr_t)(Bs + seg * 512), 16, 0, 0);
    }
    asm volatile("s_waitcnt vmcnt(0)" ::: "memory");
    __syncthreads();
#pragma unroll
    for (int ks = 0; ks < 2; ++ks) {
      bf16x8 af[4], bfr[4];
      int kk = ks * 32 + (lane >> 4) * 8;
      int rA = wr * 64 + (lane & 15);
      int rB = wc * 64 + (lane & 15);
#pragma unroll
      for (int m = 0; m < 4; ++m) af[m] = *(const bf16x8*)(As + (rA + m * 16) * 64 + kk);
#pragma unroll
      for (int n = 0; n < 4; ++n) bfr[n] = *(const bf16x8*)(Bs + (rB + n * 16) * 64 + kk);
#pragma unroll
      for (int m = 0; m < 4; ++m)
#pragma unroll
        for (int n = 0; n < 4; ++n)
          acc[m][n] = __builtin_amdgcn_mfma_f32_16x16x32_bf16(af[m], bfr[n], acc[m][n], 0, 0, 0);
    }
    __syncthreads();
  }
#pragma unroll
  for (int m = 0; m < 4; ++m)
#pragma unroll
    for (int n = 0; n < 4; ++n)
#pragma unroll
      for (int r = 0; r < 4; ++r) {
        int row = row0 + wr * 64 + m * 16 + (lane >> 4) * 4 + r;
        int col = col0 + wc * 64 + n * 16 + (lane & 15);
        float v = acc[m][n][r];
        if (mode == 0) {
          if (col < QKVZ_) C0[(long)row * QKVZ_ + col] = f2bf(v);
          else             C1[(long)row * 128 + (col - QKVZ_)] = v;
        } else {
          C1[(long)row * N + col] = v;
        }
      }
}

// ---------------- conv(4-tap causal) + SiLU + l2norm(q,k) + beta/g ----------------
__global__ __launch_bounds__(64) void k_conv(const u16* __restrict__ qkvz,
                                             const float* __restrict__ ba,
                                             const float* __restrict__ convw,
                                             const float* __restrict__ Alog,
                                             const float* __restrict__ dtb,
                                             u16* __restrict__ qn, u16* __restrict__ kn,
                                             u16* __restrict__ vb,
                                             float* __restrict__ beta, float* __restrict__ gb) {
  int bt = blockIdx.x;
  int t = bt & 2047;
  int l = threadIdx.x;
  long rb = (long)bt * QKVZ_;
#pragma unroll 1
  for (int j = 0; j < 32; ++j) {
    int c = j * 64 + l;
    float4 w = *(const float4*)(convw + c * 4);
    float a = 0.f;
#pragma unroll
    for (int d = 0; d < 4; ++d) {
      int tt = t - 3 + d;
      float x = (tt >= 0) ? bf2f(qkvz[rb + (long)(tt - t) * QKVZ_ + c]) : 0.f;
      a += x * ((const float*)&w)[d];
    }
    float y = a * sigm(a);   // SiLU
    if (j < 16) {
      float ss = y * y;
#pragma unroll
      for (int m = 1; m < 64; m <<= 1) ss += __shfl_xor(ss, m);
      float sc = rsqrtf(ss + 1e-6f);
      if (j < 8) qn[((long)bt * 8 + j) * 64 + l] = f2bf(y * sc * 0.125f);   // q * DK^-0.5
      else       kn[((long)bt * 8 + (j - 8)) * 64 + l] = f2bf(y * sc);
    } else {
      vb[((long)bt * 16 + (j - 16)) * 64 + l] = f2bf(y);
    }
  }
  if (l < 16) {
    float xb = ba[(long)bt * 128 + l];
    beta[bt * 16 + l] = sigm(xb);
    float xa = ba[(long)bt * 128 + 16 + l] + dtb[l];
    float sp = (xa > 20.f) ? xa : log1pf(__expf(xa));
    gb[bt * 16 + l] = -__expf(Alog[l]) * sp;
  }
}

// ---------------- chunk-parallel: A, forward solve -> Wl|TK, M, KtT, G ----------------
__global__ __launch_bounds__(256) void k_cpk(const u16* __restrict__ qn,
                                             const u16* __restrict__ kn,
                                             const u16* __restrict__ vb,
                                             const float* __restrict__ beta,
                                             const float* __restrict__ gb,
                                             float* __restrict__ Gbuf,
                                             u16* __restrict__ TKb, u16* __restrict__ KtTb,
                                             u16* __restrict__ WlTb, u16* __restrict__ Mb) {
  int c = blockIdx.x, hv = blockIdx.y, b = blockIdx.z;
  int hk = hv >> 1;
  int bh = b * HV_ + hv;
  int tid = threadIdx.x;
  __shared__ float Kc[64][65];
  __shared__ float Xs[64][130];
  __shared__ float As[64][65];   // A matrix; later reused for q-chunk
  __shared__ float Gl[64];
  __shared__ float Bl[64];
  long tbase = (long)b * T_ + c * 64;
  long tile = ((long)bh * NC_ + c) * 4096;

  if (tid < 64) {
    Gl[tid] = gb[(tbase + tid) * HV_ + hv];
    Bl[tid] = beta[(tbase + tid) * HV_ + hv];
  }
  __syncthreads();
  if (tid == 0) {            // inclusive cumsum of g within chunk
    float s = 0.f;
    for (int i = 0; i < 64; ++i) { s += Gl[i]; Gl[i] = s; }
  }
  __syncthreads();
  if (tid < 64) Gbuf[((long)bh * NC_ + c) * 64 + tid] = Gl[tid];

  for (int e = tid; e < 4096; e += 256) {
    int i = e >> 6, k = e & 63;
    Kc[i][k] = bf2f(kn[(tbase + i) * 512 + hk * 64 + k]);
  }
  __syncthreads();

  // A[i][s] = beta_i * exp(G_i - G_s) * (k_i . k_s), s<i
  for (int e = tid; e < 4096; e += 256) {
    int i = e >> 6, s = e & 63;
    float a = 0.f;
    if (s < i) {
      float dot = 0.f;
#pragma unroll 8
      for (int k = 0; k < 64; ++k) dot += Kc[i][k] * Kc[s][k];
      a = Bl[i] * __expf(Gl[i] - Gl[s]) * dot;
    }
    As[i][s] = a;
  }
  // RHS = [beta*V | Khat],  Khat_i = beta_i*exp(G_i)*k_i
  for (int e = tid; e < 8192; e += 256) {
    int i = e >> 7, j = e & 127;
    float x;
    if (j < 64) x = Bl[i] * bf2f(vb[(tbase + i) * 1024 + hv * 64 + j]);
    else        x = Bl[i] * __expf(Gl[i]) * Kc[i][j - 64];
    Xs[i][j] = x;
  }
  __syncthreads();

  // forward substitution: (I+A) X = RHS
  {
    int jj = tid & 127, half = tid >> 7;
    for (int s = 0; s < 63; ++s) {
      float xs = Xs[s][jj];
      for (int i2 = s + 1 + half; i2 < 64; i2 += 2)
        Xs[i2][jj] -= As[i2][s] * xs;
      __syncthreads();
    }
  }

  for (int e = tid; e < 4096; e += 256) {        // WlT[v][i] = X[i][v]
    int v = e >> 6, i = e & 63;
    WlTb[tile + e] = f2bf(Xs[i][v]);
  }
  for (int e = tid; e < 4096; e += 256) {        // TK[i][k] = X[i][64+k]
    int i = e >> 6, k = e & 63;
    TKb[tile + e] = f2bf(Xs[i][64 + k]);
  }
  float gend = Gl[63];
  for (int e = tid; e < 4096; e += 256) {        // KtT[k][i] = exp(Gend-G_i)*k_i[k]
    int k = e >> 6, i = e & 63;
    KtTb[tile + e] = f2bf(__expf(gend - Gl[i]) * Kc[i][k]);
  }
  __syncthreads();
  for (int e = tid; e < 4096; e += 256) {        // reuse As for q-chunk
    int i = e >> 6, k = e & 63;
    As[i][k] = bf2f(qn[(tbase + i) * 512 + hk * 64 + k]);
  }
  __syncthreads();
  // M[i][s] = exp(G_i-G_s)*(q_i . k_s), s<=i
  for (int e = tid; e < 4096; e += 256) {
    int i = e >> 6, s = e & 63;
    float m = 0.f;
    if (s <= i) {
      float dot = 0.f;
#pragma unroll 8
      for (int k = 0; k < 64; ++k) dot += As[i][k] * Kc[s][k];
      m = __expf(Gl[i] - Gl[s]) * dot;
    }
    Mb[tile + e] = f2bf(m);
  }
}

// ---------------- sequential over chunks (split by 8 v-blocks): W, S ----------------
__global__ __launch_bounds__(128) void k_seq(const u16* __restrict__ TKb,
                                             const u16* __restrict__ KtTb,
                                             const u16* __restrict__ WlTb,
                                             const float* __restrict__ Gbuf,
                                             u16* __restrict__ Wtb, u16* __restrict__ Stb) {
  int vblk = blockIdx.x, hv = blockIdx.y, b = blockIdx.z;
  int bh = b * HV_ + hv;
  int tid = threadIdx.x;
  __shared__ float TK[64][65];
  __shared__ float KtT[64][65];
  __shared__ float St[8][65];    // state slice S^T[v][k], fp32 across all chunks
  __shared__ float Wt[8][65];
  for (int e = tid; e < 8 * 65; e += 128) (&St[0][0])[e] = 0.f;
  __syncthreads();
  int i_ = tid & 63, half = tid >> 6;
  int v0 = vblk * 8, vb0 = half * 4;
  for (int c = 0; c < NC_; ++c) {
    long tile = ((long)bh * NC_ + c) * 4096;
    // state entering chunk c -> Stb (for the parallel O kernel)
    for (int e = tid; e < 512; e += 128) {
      int vv = e >> 6, k = e & 63;
      Stb[tile + (long)(v0 + vv) * 64 + k] = f2bf(St[vv][k]);
    }
    for (int e = tid; e < 4096; e += 128) {
      TK[e >> 6][e & 63] = bf2f(TKb[tile + e]);
      KtT[e >> 6][e & 63] = bf2f(KtTb[tile + e]);
    }
    for (int e = tid; e < 512; e += 128) {
      int vv = e >> 6, ii = e & 63;
      Wt[vv][ii] = bf2f(WlTb[tile + (long)(v0 + vv) * 64 + ii]);
    }
    __syncthreads();
    {   // W[i][v] = Wl[i][v] - sum_k TK[i][k]*S0[k][v]
      float a0 = 0, a1 = 0, a2 = 0, a3 = 0;
#pragma unroll 4
      for (int k = 0; k < 64; ++k) {
        float tk = TK[i_][k];
        a0 += St[vb0 + 0][k] * tk;
        a1 += St[vb0 + 1][k] * tk;
        a2 += St[vb0 + 2][k] * tk;
        a3 += St[vb0 + 3][k] * tk;
      }
      Wt[vb0 + 0][i_] -= a0;
      Wt[vb0 + 1][i_] -= a1;
      Wt[vb0 + 2][i_] -= a2;
      Wt[vb0 + 3][i_] -= a3;
    }
    __syncthreads();
    for (int e = tid; e < 512; e += 128) {
      int vv = e >> 6, ii = e & 63;
      Wtb[tile + (long)(v0 + vv) * 64 + ii] = f2bf(Wt[vv][ii]);
    }
    {   // S'[k][v] = gamma*S[k][v] + sum_i Kt[i][k]*W[i][v]
      float gamma = __expf(Gbuf[((long)bh * NC_ + c) * 64 + 63]);
      float a0 = 0, a1 = 0, a2 = 0, a3 = 0;
#pragma unroll 4
      for (int ii = 0; ii < 64; ++ii) {
        float kt = KtT[i_][ii];
        a0 += Wt[vb0 + 0][ii] * kt;
        a1 += Wt[vb0 + 1][ii] * kt;
        a2 += Wt[vb0 + 2][ii] * kt;
        a3 += Wt[vb0 + 3][ii] * kt;
      }
      St[vb0 + 0][i_] = gamma * St[vb0 + 0][i_] + a0;
      St[vb0 + 1][i_] = gamma * St[vb0 + 1][i_] + a1;
      St[vb0 + 2][i_] = gamma * St[vb0 + 2][i_] + a2;
      St[vb0 + 3][i_] = gamma * St[vb0 + 3][i_] + a3;
    }
    __syncthreads();
  }
}

// ---------------- chunk-parallel outputs: O = M@W + Qt@S0 ----------------
__global__ __launch_bounds__(256) void k_ok(const u16* __restrict__ Mb,
                                            const u16* __restrict__ Wtb,
                                            const u16* __restrict__ Stb,
                                            const u16* __restrict__ qn,
                                            const float* __restrict__ Gbuf,
                                            float* __restrict__ O) {
  int c = blockIdx.x, hv = blockIdx.y, b = blockIdx.z;
  int bh = b * HV_ + hv, hk = hv >> 1;
  int tid = threadIdx.x;
  __shared__ float Ms[64][65], Ws[64][65], Ss[64][65], Qs[64][65];
  __shared__ float Gl[64];
  long tile = ((long)bh * NC_ + c) * 4096;
  long tbase = (long)b * T_ + c * 64;
  if (tid < 64) Gl[tid] = Gbuf[((long)bh * NC_ + c) * 64 + tid];
  __syncthreads();
  for (int e = tid; e < 4096; e += 256) {
    int i = e >> 6, k = e & 63;
    Ms[i][k] = bf2f(Mb[tile + e]);           // M[i][s]
    Ws[i][k] = bf2f(Wtb[tile + e]);          // Wt[v][i]
    Ss[i][k] = bf2f(Stb[tile + e]);          // St[v][k]
    Qs[i][k] = __expf(Gl[i]) * bf2f(qn[(tbase + i) * 512 + hk * 64 + k]);  // Qt[i][k]
  }
  __syncthreads();
  int tx = tid & 15, ty = tid >> 4;
  int i0 = ty * 4, v0 = tx * 4;
  float acc[4][4] = {};
  for (int s = 0; s < 64; ++s) {
    float mv[4], wv[4];
#pragma unroll
    for (int r = 0; r < 4; ++r) { mv[r] = Ms[i0 + r][s]; wv[r] = Ws[v0 + r][s]; }
#pragma unroll
    for (int r = 0; r < 4; ++r)
#pragma unroll
      for (int q = 0; q < 4; ++q) acc[r][q] += mv[r] * wv[q];
#pragma unroll
    for (int r = 0; r < 4; ++r) { mv[r] = Qs[i0 + r][s]; wv[r] = Ss[v0 + r][s]; }
#pragma unroll
    for (int r = 0; r < 4; ++r)
#pragma unroll
      for (int q = 0; q < 4; ++q) acc[r][q] += mv[r] * wv[q];
  }
#pragma unroll
  for (int r = 0; r < 4; ++r) {
    float4 o4 = make_float4(acc[r][0], acc[r][1], acc[r][2], acc[r][3]);
    *(float4*)&O[((tbase + i0 + r) * HV_ + hv) * 64 + v0] = o4;
  }
}

// ---------------- gated RMSNorm: rmsnorm(o)*w*silu(z) -> bf16 ----------------
__global__ __launch_bounds__(256) void k_rms(const float* __restrict__ O,
                                             const u16* __restrict__ qkvz,
                                             const float* __restrict__ normw,
                                             u16* __restrict__ on) {
  int bt = blockIdx.x;
  int tid = threadIdx.x;
  __shared__ float ps[256];
  __shared__ float rstd[16];
  float4 o4 = *(const float4*)&O[(long)bt * 1024 + tid * 4];
  ps[tid] = o4.x * o4.x + o4.y * o4.y + o4.z * o4.z + o4.w * o4.w;
  __syncthreads();
  if (tid < 16) {
    float s = 0.f;
#pragma unroll
    for (int u = 0; u < 16; ++u) s += ps[tid * 16 + u];
    rstd[tid] = rsqrtf(s * (1.f / 64.f) + 1e-6f);
  }
  __syncthreads();
  float rs = rstd[tid >> 4];
  u16x4 ov;
#pragma unroll
  for (int j = 0; j < 4; ++j) {
    int idx = tid * 4 + j;
    float z = bf2f(qkvz[(long)bt * QKVZ_ + 2048 + idx]);
    float val = ((const float*)&o4)[j] * rs * normw[idx & 63] * (z * sigm(z));
    ((u16*)&ov)[j] = f2bf(val);
  }
  *(u16x4*)(on + (long)bt * 1024 + tid * 4) = ov;
}

// ---------------- host launch ----------------
extern "C" void kernel_launch(void* const* d_in, const int* in_sizes, int n_in,
                              void* d_out, int out_size, void* d_ws, size_t ws_size,
                              hipStream_t stream) {
  const float* hs    = (const float*)d_in[0];
  const float* Wqkv  = (const float*)d_in[1];
  const float* Wz    = (const float*)d_in[2];
  const float* Wb    = (const float*)d_in[3];
  const float* Wa    = (const float*)d_in[4];
  const float* dtb   = (const float*)d_in[5];
  const float* Alog  = (const float*)d_in[6];
  const float* convw = (const float*)d_in[7];
  const float* normw = (const float*)d_in[8];
  const float* Wout  = (const float*)d_in[9];
  float* out = (float*)d_out;

  char* p = (char*)d_ws;
  auto take = [&](size_t bytes) {
    char* q = p;
    p += (bytes + 255) & ~(size_t)255;
    return (void*)q;
  };
  u16*   qkvz  = (u16*)take((size_t)BT_ * QKVZ_ * 2);
  float* ba    = (float*)take((size_t)BT_ * 128 * 4);
  u16*   hsb   = (u16*)take((size_t)BT_ * 1024 * 2);
  u16*   wcatT = (u16*)take((size_t)NCOL_ * 1024 * 2);
  u16*   woutT = (u16*)take((size_t)1024 * 1024 * 2);
  u16*   qn    = (u16*)take((size_t)BT_ * 512 * 2);
  u16*   kn    = (u16*)take((size_t)BT_ * 512 * 2);
  u16*   vbuf  = (u16*)take((size_t)BT_ * 1024 * 2);
  float* beta  = (float*)take((size_t)BT_ * 16 * 4);
  float* gbuf  = (float*)take((size_t)BT_ * 16 * 4);
  float* Gcum  = (float*)take((size_t)1024 * 64 * 4);
  u16*   TKb   = (u16*)take((size_t)1024 * 4096 * 2);
  u16*   KtTb  = (u16*)take((size_t)1024 * 4096 * 2);
  u16*   WlTb  = (u16*)take((size_t)1024 * 4096 * 2);
  u16*   Mb    = (u16*)take((size_t)1024 * 4096 * 2);
  u16*   Wtb   = (u16*)take((size_t)1024 * 4096 * 2);
  u16*   Stb   = (u16*)take((size_t)1024 * 4096 * 2);
  float* Obuf  = (float*)take((size_t)BT_ * 1024 * 4);
  u16*   onb   = (u16*)take((size_t)BT_ * 1024 * 2);

  k_cast_hs<<<dim3(4096), dim3(256), 0, stream>>>(hs, hsb);
  k_wcatT<<<dim3(100, 32), dim3(256), 0, stream>>>(Wqkv, Wz, Wb, Wa, wcatT);
  k_tcast<<<dim3(32, 32), dim3(256), 0, stream>>>(Wout, woutT, 1024, 1024);
  k_gemm<<<dim3(25, 32), dim3(256), 0, stream>>>(hsb, wcatT, qkvz, ba, 4096, NCOL_, 1024, 0);
  k_conv<<<dim3(4096), dim3(64), 0, stream>>>(qkvz, ba, convw, Alog, dtb, qn, kn, vbuf, beta, gbuf);
  k_cpk<<<dim3(32, 16, 2), dim3(256), 0, stream>>>(qn, kn, vbuf, beta, gbuf, Gcum, TKb, KtTb, WlTb, Mb);
  k_seq<<<dim3(8, 16, 2), dim3(128), 0, stream>>>(TKb, KtTb, WlTb, Gcum, Wtb, Stb);
  k_ok<<<dim3(32, 16, 2), dim3(256), 0, stream>>>(Mb, Wtb, Stb, qn, Gcum, Obuf);
  k_rms<<<dim3(4096), dim3(256), 0, stream>>>(Obuf, qkvz, normw, onb);
  k_gemm<<<dim3(8, 32), dim3(256), 0, stream>>>(onb, woutT, (u16*)nullptr, out, 4096, 1024, 1024, 1);
}

// Round 3
// 507.422 us; speedup vs baseline: 1.3342x; 1.3342x over previous
//
#include <hip/hip_runtime.h>
#include <hip/hip_bf16.h>

// Qwen3.5 GatedDeltaNet forward, chunked delta-rule formulation.
// B=2,T=2048,D=1024, HV=16,HK=8,DK=DV=64, chunk=64 (32 chunks).
// Round 3: fix k_ok2 M-prefetch OOB (tid*32 -> tid*16; LDS stomp of Ss).

typedef unsigned short u16;
typedef float f32x4 __attribute__((ext_vector_type(4)));
typedef short bf16x8 __attribute__((ext_vector_type(8)));
typedef u16 u16x4 __attribute__((ext_vector_type(4)));
typedef const __attribute__((address_space(1))) void* gptr_t;
typedef __attribute__((address_space(3))) void* lptr_t;

#define B_    2
#define T_    2048
#define HV_   16
#define HK_   8
#define NC_   32      // chunks
#define BT_   4096
#define QKVZ_ 3072
#define NCOL_ 3200    // gemm1 padded N (2048 qkv + 1024 z + 128 beta/a pad)

__device__ __forceinline__ u16 f2bf(float f) {
  return __builtin_bit_cast(u16, __float2bfloat16(f));
}
__device__ __forceinline__ float bf2f(u16 u) {
  return __bfloat162float(__builtin_bit_cast(__hip_bfloat16, u));
}
__device__ __forceinline__ float sigm(float x) { return 1.f / (1.f + __expf(-x)); }

// ---------------- cast hs -> bf16 ----------------
__global__ __launch_bounds__(256) void k_cast_hs(const float* __restrict__ in,
                                                 u16* __restrict__ out) {
  int i = (blockIdx.x * 256 + threadIdx.x) * 4;
  float4 v = *(const float4*)(in + i);
  u16x4 o; o.x = f2bf(v.x); o.y = f2bf(v.y); o.z = f2bf(v.z); o.w = f2bf(v.w);
  *(u16x4*)(out + i) = o;
}

// ---------------- generic transpose+cast: dst[c][r] = src[r][c] ----------------
__global__ __launch_bounds__(256) void k_tcast(const float* __restrict__ src,
                                               u16* __restrict__ dst, int R, int C) {
  __shared__ float tile[32][33];
  int c0 = blockIdx.x * 32, r0 = blockIdx.y * 32;
  int cx = threadIdx.x & 31, ry = threadIdx.x >> 5;
#pragma unroll
  for (int j = 0; j < 4; ++j)
    tile[ry * 4 + j][cx] = src[(long)(r0 + ry * 4 + j) * C + c0 + cx];
  __syncthreads();
#pragma unroll
  for (int j = 0; j < 4; ++j)
    dst[(long)(c0 + ry * 4 + j) * R + r0 + cx] = f2bf(tile[cx][ry * 4 + j]);
}

// ---------------- build Wcat^T [3200][1024] from W_qkv|W_z|W_b|W_a ----------------
__global__ __launch_bounds__(256) void k_wcatT(const float* __restrict__ Wqkv,
                                               const float* __restrict__ Wz,
                                               const float* __restrict__ Wb,
                                               const float* __restrict__ Wa,
                                               u16* __restrict__ dst) {
  __shared__ float tile[32][33];
  int n0 = blockIdx.x * 32, k0 = blockIdx.y * 32;
  int cx = threadIdx.x & 31, ry = threadIdx.x >> 5;
#pragma unroll
  for (int j = 0; j < 4; ++j) {
    int kk = k0 + ry * 4 + j;
    int n = n0 + cx;
    float v;
    if (n < 2048)      v = Wqkv[(long)kk * 2048 + n];
    else if (n < 3072) v = Wz[(long)kk * 1024 + (n - 2048)];
    else if (n < 3088) v = Wb[kk * 16 + (n - 3072)];
    else if (n < 3104) v = Wa[kk * 16 + (n - 3088)];
    else               v = 0.f;
    tile[ry * 4 + j][cx] = v;
  }
  __syncthreads();
#pragma unroll
  for (int j = 0; j < 4; ++j)
    dst[(long)(n0 + ry * 4 + j) * 1024 + k0 + cx] = f2bf(tile[cx][ry * 4 + j]);
}

// ---------------- bf16 MFMA GEMM: C[M,N] = A[M,K] @ Bt[N,K]^T ----------------
__global__ __launch_bounds__(256) void k_gemm(const u16* __restrict__ A,
                                              const u16* __restrict__ Bt,
                                              u16* __restrict__ C0,
                                              float* __restrict__ C1,
                                              int M, int N, int K, int mode) {
  __shared__ u16 As[128 * 64];
  __shared__ u16 Bs[128 * 64];
  int tid = threadIdx.x;
  int wid = tid >> 6, lane = tid & 63;
  int row0 = blockIdx.y * 128, col0 = blockIdx.x * 128;
  int wr = wid >> 1, wc = wid & 1;
  f32x4 acc[4][4];
#pragma unroll
  for (int m = 0; m < 4; ++m)
#pragma unroll
    for (int n = 0; n < 4; ++n) acc[m][n] = (f32x4){0.f, 0.f, 0.f, 0.f};

  int srow = lane >> 3;
  int skoff = (lane & 7) * 8;

  for (int k0 = 0; k0 < K; k0 += 64) {
#pragma unroll
    for (int it = 0; it < 4; ++it) {
      int seg = wid * 4 + it;
      int r = seg * 8 + srow;
      const u16* gA = A + (long)(row0 + r) * K + k0 + skoff;
      const u16* gB = Bt + (long)(col0 + r) * K + k0 + skoff;
      __builtin_amdgcn_global_load_lds((gptr_t)gA, (lptr_t)(As + seg * 512), 16, 0, 0);
      __builtin_amdgcn_global_load_lds((gptr_t)gB, (lptr_t)(Bs + seg * 512), 16, 0, 0);
    }
    asm volatile("s_waitcnt vmcnt(0)" ::: "memory");
    __syncthreads();
#pragma unroll
    for (int ks = 0; ks < 2; ++ks) {
      bf16x8 af[4], bfr[4];
      int kk = ks * 32 + (lane >> 4) * 8;
      int rA = wr * 64 + (lane & 15);
      int rB = wc * 64 + (lane & 15);
#pragma unroll
      for (int m = 0; m < 4; ++m) af[m] = *(const bf16x8*)(As + (rA + m * 16) * 64 + kk);
#pragma unroll
      for (int n = 0; n < 4; ++n) bfr[n] = *(const bf16x8*)(Bs + (rB + n * 16) * 64 + kk);
#pragma unroll
      for (int m = 0; m < 4; ++m)
#pragma unroll
        for (int n = 0; n < 4; ++n)
          acc[m][n] = __builtin_amdgcn_mfma_f32_16x16x32_bf16(af[m], bfr[n], acc[m][n], 0, 0, 0);
    }
    __syncthreads();
  }
#pragma unroll
  for (int m = 0; m < 4; ++m)
#pragma unroll
    for (int n = 0; n < 4; ++n)
#pragma unroll
      for (int r = 0; r < 4; ++r) {
        int row = row0 + wr * 64 + m * 16 + (lane >> 4) * 4 + r;
        int col = col0 + wc * 64 + n * 16 + (lane & 15);
        float v = acc[m][n][r];
        if (mode == 0) {
          if (col < QKVZ_) C0[(long)row * QKVZ_ + col] = f2bf(v);
          else             C1[(long)row * 128 + (col - QKVZ_)] = v;
        } else {
          C1[(long)row * N + col] = v;
        }
      }
}

// ---------------- conv(4-tap causal) + SiLU + l2norm(q,k) + beta/g ----------------
__global__ __launch_bounds__(64) void k_conv(const u16* __restrict__ qkvz,
                                             const float* __restrict__ ba,
                                             const float* __restrict__ convw,
                                             const float* __restrict__ Alog,
                                             const float* __restrict__ dtb,
                                             u16* __restrict__ qn, u16* __restrict__ kn,
                                             u16* __restrict__ vb,
                                             float* __restrict__ beta, float* __restrict__ gb) {
  int bt = blockIdx.x;
  int t = bt & 2047;
  int l = threadIdx.x;
  long rb = (long)bt * QKVZ_;
#pragma unroll 1
  for (int j = 0; j < 32; ++j) {
    int c = j * 64 + l;
    float4 w = *(const float4*)(convw + c * 4);
    float a = 0.f;
#pragma unroll
    for (int d = 0; d < 4; ++d) {
      int tt = t - 3 + d;
      float x = (tt >= 0) ? bf2f(qkvz[rb + (long)(tt - t) * QKVZ_ + c]) : 0.f;
      a += x * ((const float*)&w)[d];
    }
    float y = a * sigm(a);   // SiLU
    if (j < 16) {
      float ss = y * y;
#pragma unroll
      for (int m = 1; m < 64; m <<= 1) ss += __shfl_xor(ss, m);
      float sc = rsqrtf(ss + 1e-6f);
      if (j < 8) qn[((long)bt * 8 + j) * 64 + l] = f2bf(y * sc * 0.125f);
      else       kn[((long)bt * 8 + (j - 8)) * 64 + l] = f2bf(y * sc);
    } else {
      vb[((long)bt * 16 + (j - 16)) * 64 + l] = f2bf(y);
    }
  }
  if (l < 16) {
    float xb = ba[(long)bt * 128 + l];
    beta[bt * 16 + l] = sigm(xb);
    float xa = ba[(long)bt * 128 + 16 + l] + dtb[l];
    float sp = (xa > 20.f) ? xa : log1pf(__expf(xa));
    gb[bt * 16 + l] = -__expf(Alog[l]) * sp;
  }
}

// ---------------- chunk-parallel: A, solve -> Wl|TK, P=KtT@TK, B=KtT@Wl, M, G ----------------
__global__ __launch_bounds__(256) void k_cpk(const u16* __restrict__ qn,
                                             const u16* __restrict__ kn,
                                             const u16* __restrict__ vb,
                                             const float* __restrict__ beta,
                                             const float* __restrict__ gb,
                                             float* __restrict__ Gbuf,
                                             u16* __restrict__ TKb,
                                             u16* __restrict__ WlTb, u16* __restrict__ Mb,
                                             u16* __restrict__ Pb, u16* __restrict__ Bb) {
  int c = blockIdx.x, hv = blockIdx.y, b = blockIdx.z;
  int hk = hv >> 1;
  int bh = b * HV_ + hv;
  int tid = threadIdx.x;
  __shared__ float Kc[64][65];
  __shared__ float Xs[64][132];
  __shared__ float As[64][68];   // A matrix; then Kt staging; then q-chunk
  __shared__ float Gl[64];
  __shared__ float Bl[64];
  __shared__ float Ff[64];
  long tbase = (long)b * T_ + c * 64;
  long tile = ((long)bh * NC_ + c) * 4096;

  if (tid < 64) {
    Gl[tid] = gb[(tbase + tid) * HV_ + hv];
    Bl[tid] = beta[(tbase + tid) * HV_ + hv];
  }
  __syncthreads();
  if (tid == 0) {            // inclusive cumsum of g within chunk
    float s = 0.f;
    for (int i = 0; i < 64; ++i) { s += Gl[i]; Gl[i] = s; }
  }
  __syncthreads();
  if (tid < 64) Gbuf[((long)bh * NC_ + c) * 64 + tid] = Gl[tid];

  for (int e = tid; e < 4096; e += 256) {
    int i = e >> 6, k = e & 63;
    Kc[i][k] = bf2f(kn[(tbase + i) * 512 + hk * 64 + k]);
  }
  __syncthreads();

  // A[i][s] = beta_i * exp(G_i - G_s) * (k_i . k_s), s<i
  for (int e = tid; e < 4096; e += 256) {
    int i = e >> 6, s = e & 63;
    float a = 0.f;
    if (s < i) {
      float dot = 0.f;
#pragma unroll 8
      for (int k = 0; k < 64; ++k) dot += Kc[i][k] * Kc[s][k];
      a = Bl[i] * __expf(Gl[i] - Gl[s]) * dot;
    }
    As[i][s] = a;
  }
  // RHS = [beta*V | Khat],  Khat_i = beta_i*exp(G_i)*k_i
  for (int e = tid; e < 8192; e += 256) {
    int i = e >> 7, j = e & 127;
    float x;
    if (j < 64) x = Bl[i] * bf2f(vb[(tbase + i) * 1024 + hv * 64 + j]);
    else        x = Bl[i] * __expf(Gl[i]) * Kc[i][j - 64];
    Xs[i][j] = x;
  }
  __syncthreads();

  // forward substitution: (I+A) X = RHS
  {
    int jj = tid & 127, half = tid >> 7;
    for (int s = 0; s < 63; ++s) {
      float xs = Xs[s][jj];
      for (int i2 = s + 1 + half; i2 < 64; i2 += 2)
        Xs[i2][jj] -= As[i2][s] * xs;
      __syncthreads();
    }
  }

  for (int e = tid; e < 4096; e += 256) {        // WlT[v][i] = X[i][v]
    int v = e >> 6, i = e & 63;
    WlTb[tile + e] = f2bf(Xs[i][v]);
  }
  for (int e = tid; e < 4096; e += 256) {        // TK[i][k] = X[i][64+k]
    int i = e >> 6, k = e & 63;
    TKb[tile + e] = f2bf(Xs[i][64 + k]);
  }
  float gend = Gl[63];
  if (tid < 64) Ff[tid] = __expf(gend - Gl[tid]);
  __syncthreads();
  // stage Kt[i][r] = Ff[i]*Kc[i][r] into As
  for (int e = tid; e < 4096; e += 256) {
    int i = e >> 6, r = e & 63;
    As[i][r] = Ff[i] * Kc[i][r];
  }
  __syncthreads();
  // Y[r][c2] = sum_i Kt[i][r] * Xs[i][c2];  c2<64 -> B[r][v], c2>=64 -> P^T[k2][r]
  {
    int tx = tid & 15, ty = tid >> 4;
    int r0 = ty * 4, c0 = tx * 8;
    float acc[4][8] = {};
    for (int i = 0; i < 64; ++i) {
      f32x4 kt = *(const f32x4*)&As[i][r0];
      f32x4 x0 = *(const f32x4*)&Xs[i][c0];
      f32x4 x1 = *(const f32x4*)&Xs[i][c0 + 4];
#pragma unroll
      for (int r = 0; r < 4; ++r) {
#pragma unroll
        for (int q = 0; q < 4; ++q) acc[r][q] += kt[r] * x0[q];
#pragma unroll
        for (int q = 0; q < 4; ++q) acc[r][4 + q] += kt[r] * x1[q];
      }
    }
    if (c0 < 64) {       // B[r][v] row-major
#pragma unroll
      for (int r = 0; r < 4; ++r)
#pragma unroll
        for (int q = 0; q < 8; ++q)
          Bb[tile + (long)(r0 + r) * 64 + c0 + q] = f2bf(acc[r][q]);
    } else {             // P^T[k2][r]
#pragma unroll
      for (int q = 0; q < 8; ++q)
#pragma unroll
        for (int r = 0; r < 4; ++r)
          Pb[tile + (long)(c0 - 64 + q) * 64 + r0 + r] = f2bf(acc[r][q]);
    }
  }
  __syncthreads();
  for (int e = tid; e < 4096; e += 256) {        // reuse As for q-chunk
    int i = e >> 6, k = e & 63;
    As[i][k] = bf2f(qn[(tbase + i) * 512 + hk * 64 + k]);
  }
  __syncthreads();
  // M[i][s] = exp(G_i-G_s)*(q_i . k_s), s<=i
  for (int e = tid; e < 4096; e += 256) {
    int i = e >> 6, s = e & 63;
    float m = 0.f;
    if (s <= i) {
      float dot = 0.f;
#pragma unroll 8
      for (int k = 0; k < 64; ++k) dot += As[i][k] * Kc[s][k];
      m = __expf(Gl[i] - Gl[s]) * dot;
    }
    Mb[tile + e] = f2bf(m);
  }
}

// ---------------- serial scan over chunks: S' = g*S - P@S + B ----------------
__global__ __launch_bounds__(256) void k_seq2(const u16* __restrict__ Pb,
                                              const u16* __restrict__ Bb,
                                              const float* __restrict__ Gbuf,
                                              u16* __restrict__ Stb) {
  int vblk = blockIdx.x, bh = blockIdx.y;
  int tid = threadIdx.x;
  __shared__ u16 Abf[2][4096];
  __shared__ u16 Bbf[2][512];
  __shared__ float S_lds[64][10];
  __shared__ float gam[NC_];
  int i_ = tid & 63, vg = tid >> 6;    // out-row i_, v pair index vg
  int wv = tid >> 6, ln = tid & 63;
  if (tid < NC_) gam[tid] = __expf(Gbuf[((long)bh * NC_ + tid) * 64 + 63]);
  for (int e = tid; e < 640; e += 256) ((float*)S_lds)[e] = 0.f;
  float a0 = 0.f, a1 = 0.f;
  // prologue: load chunk 0
  {
    long tl = (long)bh * NC_ * 4096;
    const u16* gA = Pb + tl + wv * 512 + ln * 8;
    __builtin_amdgcn_global_load_lds((gptr_t)gA, (lptr_t)&Abf[0][wv * 512], 16, 0, 0);
    __builtin_amdgcn_global_load_lds((gptr_t)(gA + 2048), (lptr_t)&Abf[0][2048 + wv * 512], 16, 0, 0);
    int ii = tid >> 2, vp = tid & 3;
    const u16* gB = Bb + tl + ii * 64 + vblk * 8 + vp * 2;
    __builtin_amdgcn_global_load_lds((gptr_t)gB, (lptr_t)&Bbf[0][wv * 128], 4, 0, 0);
  }
  for (int c = 0; c < NC_; ++c) {
    int cur = c & 1;
    asm volatile("s_waitcnt vmcnt(0)" ::: "memory");
    __syncthreads();
    if (c + 1 < NC_) {
      long tl = ((long)bh * NC_ + c + 1) * 4096;
      const u16* gA = Pb + tl + wv * 512 + ln * 8;
      __builtin_amdgcn_global_load_lds((gptr_t)gA, (lptr_t)&Abf[cur ^ 1][wv * 512], 16, 0, 0);
      __builtin_amdgcn_global_load_lds((gptr_t)(gA + 2048), (lptr_t)&Abf[cur ^ 1][2048 + wv * 512], 16, 0, 0);
      int ii = tid >> 2, vp = tid & 3;
      const u16* gB = Bb + tl + ii * 64 + vblk * 8 + vp * 2;
      __builtin_amdgcn_global_load_lds((gptr_t)gB, (lptr_t)&Bbf[cur ^ 1][wv * 128], 4, 0, 0);
    }
    // store S_c (state entering chunk c) for k_ok2
    {
      long stile = ((long)bh * NC_ + c) * 4096;
      int v0 = vblk * 8 + vg * 2;
      Stb[stile + (long)v0 * 64 + i_] = f2bf(a0);
      Stb[stile + (long)(v0 + 1) * 64 + i_] = f2bf(a1);
    }
    float g = gam[c];
    float n0 = 0.f, n1 = 0.f;
#pragma unroll 8
    for (int k = 0; k < 64; ++k) {
      float p = bf2f(Abf[cur][k * 64 + i_]);
      float2 sv = *(const float2*)&S_lds[k][vg * 2];
      n0 += p * sv.x;
      n1 += p * sv.y;
    }
    float b0 = bf2f(Bbf[cur][i_ * 8 + vg * 2]);
    float b1 = bf2f(Bbf[cur][i_ * 8 + vg * 2 + 1]);
    a0 = g * a0 - n0 + b0;
    a1 = g * a1 - n1 + b1;
    __syncthreads();
    S_lds[i_][vg * 2] = a0;
    S_lds[i_][vg * 2 + 1] = a1;
  }
}

// ---------------- chunk-parallel outputs: W = Wl - TK@S;  O = M@W + Qt@S ----------------
__global__ __launch_bounds__(256) void k_ok2(const u16* __restrict__ Mb,
                                             const u16* __restrict__ TKb,
                                             const u16* __restrict__ WlTb,
                                             const u16* __restrict__ Stb,
                                             const u16* __restrict__ qn,
                                             const float* __restrict__ Gbuf,
                                             float* __restrict__ O) {
  int c = blockIdx.x, hv = blockIdx.y, b = blockIdx.z;
  int bh = b * HV_ + hv, hk = hv >> 1;
  int tid = threadIdx.x;
  __shared__ float TKt[64][68];   // TK^T[k][i]; later M^T[s][i]
  __shared__ float Ss[64][68];    // S[k][v]
  __shared__ float Ws[64][68];    // Wl[i][v] -> W[i][v]
  __shared__ float Qt[64][68];    // Qt^T[k][i]
  __shared__ float Gl[64];
  long tile = ((long)bh * NC_ + c) * 4096;
  long tbase = (long)b * T_ + c * 64;
  if (tid < 64) Gl[tid] = Gbuf[((long)bh * NC_ + c) * 64 + tid];
  // prefetch M into regs (16 u16 per thread; 256*16 = 4096 = full tile)
  bf16x8 mreg[2];
#pragma unroll
  for (int j = 0; j < 2; ++j) mreg[j] = *(const bf16x8*)(Mb + tile + tid * 16 + j * 8);
  __syncthreads();
  for (int e = tid; e < 4096; e += 256) {
    int i = e >> 6, k = e & 63;
    TKt[k][i] = bf2f(TKb[tile + e]);                       // TK[i][k] -> [k][i]
    Qt[k][i] = __expf(Gl[i]) * bf2f(qn[(tbase + i) * 512 + hk * 64 + k]);
  }
  for (int e = tid; e < 4096; e += 256) {
    int v = e >> 6, x = e & 63;
    Ss[x][v] = bf2f(Stb[tile + e]);                        // St[v][k] -> S[k][v]
    Ws[x][v] = bf2f(WlTb[tile + e]);                       // WlT[v][i] -> Wl[i][v]
  }
  __syncthreads();
  int tx = tid & 15, ty = tid >> 4;
  int i0 = ty * 4, v0 = tx * 4;
  // phase1: W = Wl - TK@S
  float w[4][4];
#pragma unroll
  for (int r = 0; r < 4; ++r) *(f32x4*)w[r] = *(const f32x4*)&Ws[i0 + r][v0];
  for (int k = 0; k < 64; ++k) {
    f32x4 tk = *(const f32x4*)&TKt[k][i0];
    f32x4 sv = *(const f32x4*)&Ss[k][v0];
#pragma unroll
    for (int r = 0; r < 4; ++r)
#pragma unroll
      for (int q = 0; q < 4; ++q) w[r][q] -= tk[r] * sv[q];
  }
  __syncthreads();
#pragma unroll
  for (int r = 0; r < 4; ++r) *(f32x4*)&Ws[i0 + r][v0] = *(const f32x4*)w[r];
  // unpack M into TKt as M^T[s][i]  (e = linear index i*64+s)
#pragma unroll
  for (int j = 0; j < 2; ++j) {
#pragma unroll
    for (int l = 0; l < 8; ++l) {
      int e = tid * 16 + j * 8 + l;
      TKt[e & 63][e >> 6] = bf2f((u16)mreg[j][l]);
    }
  }
  __syncthreads();
  // phase2: O = M@W + Qt@S
  float o[4][4] = {};
  for (int s = 0; s < 64; ++s) {
    f32x4 mv = *(const f32x4*)&TKt[s][i0];
    f32x4 wv = *(const f32x4*)&Ws[s][v0];
#pragma unroll
    for (int r = 0; r < 4; ++r)
#pragma unroll
      for (int q = 0; q < 4; ++q) o[r][q] += mv[r] * wv[q];
  }
  for (int k = 0; k < 64; ++k) {
    f32x4 qv = *(const f32x4*)&Qt[k][i0];
    f32x4 sv = *(const f32x4*)&Ss[k][v0];
#pragma unroll
    for (int r = 0; r < 4; ++r)
#pragma unroll
      for (int q = 0; q < 4; ++q) o[r][q] += qv[r] * sv[q];
  }
#pragma unroll
  for (int r = 0; r < 4; ++r) {
    float4 o4 = make_float4(o[r][0], o[r][1], o[r][2], o[r][3]);
    *(float4*)&O[((tbase + i0 + r) * HV_ + hv) * 64 + v0] = o4;
  }
}

// ---------------- gated RMSNorm: rmsnorm(o)*w*silu(z) -> bf16 ----------------
__global__ __launch_bounds__(256) void k_rms(const float* __restrict__ O,
                                             const u16* __restrict__ qkvz,
                                             const float* __restrict__ normw,
                                             u16* __restrict__ on) {
  int bt = blockIdx.x;
  int tid = threadIdx.x;
  __shared__ float ps[256];
  __shared__ float rstd[16];
  float4 o4 = *(const float4*)&O[(long)bt * 1024 + tid * 4];
  ps[tid] = o4.x * o4.x + o4.y * o4.y + o4.z * o4.z + o4.w * o4.w;
  __syncthreads();
  if (tid < 16) {
    float s = 0.f;
#pragma unroll
    for (int u = 0; u < 16; ++u) s += ps[tid * 16 + u];
    rstd[tid] = rsqrtf(s * (1.f / 64.f) + 1e-6f);
  }
  __syncthreads();
  float rs = rstd[tid >> 4];
  u16x4 ov;
#pragma unroll
  for (int j = 0; j < 4; ++j) {
    int idx = tid * 4 + j;
    float z = bf2f(qkvz[(long)bt * QKVZ_ + 2048 + idx]);
    float val = ((const float*)&o4)[j] * rs * normw[idx & 63] * (z * sigm(z));
    ((u16*)&ov)[j] = f2bf(val);
  }
  *(u16x4*)(on + (long)bt * 1024 + tid * 4) = ov;
}

// ---------------- host launch ----------------
extern "C" void kernel_launch(void* const* d_in, const int* in_sizes, int n_in,
                              void* d_out, int out_size, void* d_ws, size_t ws_size,
                              hipStream_t stream) {
  const float* hs    = (const float*)d_in[0];
  const float* Wqkv  = (const float*)d_in[1];
  const float* Wz    = (const float*)d_in[2];
  const float* Wb    = (const float*)d_in[3];
  const float* Wa    = (const float*)d_in[4];
  const float* dtb   = (const float*)d_in[5];
  const float* Alog  = (const float*)d_in[6];
  const float* convw = (const float*)d_in[7];
  const float* normw = (const float*)d_in[8];
  const float* Wout  = (const float*)d_in[9];
  float* out = (float*)d_out;

  char* p = (char*)d_ws;
  auto take = [&](size_t bytes) {
    char* q = p;
    p += (bytes + 255) & ~(size_t)255;
    return (void*)q;
  };
  u16*   qkvz  = (u16*)take((size_t)BT_ * QKVZ_ * 2);
  float* ba    = (float*)take((size_t)BT_ * 128 * 4);
  u16*   hsb   = (u16*)take((size_t)BT_ * 1024 * 2);
  u16*   wcatT = (u16*)take((size_t)NCOL_ * 1024 * 2);
  u16*   woutT = (u16*)take((size_t)1024 * 1024 * 2);
  u16*   qn    = (u16*)take((size_t)BT_ * 512 * 2);
  u16*   kn    = (u16*)take((size_t)BT_ * 512 * 2);
  u16*   vbuf  = (u16*)take((size_t)BT_ * 1024 * 2);
  float* beta  = (float*)take((size_t)BT_ * 16 * 4);
  float* gbuf  = (float*)take((size_t)BT_ * 16 * 4);
  float* Gcum  = (float*)take((size_t)1024 * 64 * 4);
  u16*   TKb   = (u16*)take((size_t)1024 * 4096 * 2);
  u16*   WlTb  = (u16*)take((size_t)1024 * 4096 * 2);
  u16*   Mb    = (u16*)take((size_t)1024 * 4096 * 2);
  u16*   Pb    = (u16*)take((size_t)1024 * 4096 * 2);
  u16*   Bb    = (u16*)take((size_t)1024 * 4096 * 2);
  u16*   Stb   = (u16*)take((size_t)1024 * 4096 * 2);
  float* Obuf  = (float*)take((size_t)BT_ * 1024 * 4);
  u16*   onb   = (u16*)take((size_t)BT_ * 1024 * 2);

  k_cast_hs<<<dim3(4096), dim3(256), 0, stream>>>(hs, hsb);
  k_wcatT<<<dim3(100, 32), dim3(256), 0, stream>>>(Wqkv, Wz, Wb, Wa, wcatT);
  k_tcast<<<dim3(32, 32), dim3(256), 0, stream>>>(Wout, woutT, 1024, 1024);
  k_gemm<<<dim3(25, 32), dim3(256), 0, stream>>>(hsb, wcatT, qkvz, ba, 4096, NCOL_, 1024, 0);
  k_conv<<<dim3(4096), dim3(64), 0, stream>>>(qkvz, ba, convw, Alog, dtb, qn, kn, vbuf, beta, gbuf);
  k_cpk<<<dim3(32, 16, 2), dim3(256), 0, stream>>>(qn, kn, vbuf, beta, gbuf, Gcum, TKb, WlTb, Mb, Pb, Bb);
  k_seq2<<<dim3(8, 32), dim3(256), 0, stream>>>(Pb, Bb, Gcum, Stb);
  k_ok2<<<dim3(32, 16, 2), dim3(256), 0, stream>>>(Mb, TKb, WlTb, Stb, qn, Gcum, Obuf);
  k_rms<<<dim3(4096), dim3(256), 0, stream>>>(Obuf, qkvz, normw, onb);
  k_gemm<<<dim3(8, 32), dim3(256), 0, stream>>>(onb, woutT, (u16*)nullptr, out, 4096, 1024, 1024, 1);
}

// Round 5
// 362.984 us; speedup vs baseline: 1.8651x; 1.3979x over previous
//
#include <hip/hip_runtime.h>
#include <hip/hip_bf16.h>

// Qwen3.5 GatedDeltaNet forward, chunked delta-rule formulation.
// B=2,T=2048,D=1024, HV=16,HK=8,DK=DV=64, chunk=64 (32 chunks).
// Round 5: identical to round 4 (bench was GPU-acquisition timeout).
//          k_cpk2 = MFMA (A, M, P, B products) + blocked triangular solve.

typedef unsigned short u16;
typedef float f32x4 __attribute__((ext_vector_type(4)));
typedef short bf16x8 __attribute__((ext_vector_type(8)));
typedef u16 u16x4 __attribute__((ext_vector_type(4)));
typedef const __attribute__((address_space(1))) void* gptr_t;
typedef __attribute__((address_space(3))) void* lptr_t;

#define B_    2
#define T_    2048
#define HV_   16
#define HK_   8
#define NC_   32      // chunks
#define BT_   4096
#define QKVZ_ 3072
#define NCOL_ 3200    // gemm1 padded N (2048 qkv + 1024 z + 128 beta/a pad)

__device__ __forceinline__ u16 f2bf(float f) {
  return __builtin_bit_cast(u16, __float2bfloat16(f));
}
__device__ __forceinline__ float bf2f(u16 u) {
  return __bfloat162float(__builtin_bit_cast(__hip_bfloat16, u));
}
__device__ __forceinline__ float sigm(float x) { return 1.f / (1.f + __expf(-x)); }

// ---------------- cast hs -> bf16 ----------------
__global__ __launch_bounds__(256) void k_cast_hs(const float* __restrict__ in,
                                                 u16* __restrict__ out) {
  int i = (blockIdx.x * 256 + threadIdx.x) * 4;
  float4 v = *(const float4*)(in + i);
  u16x4 o; o.x = f2bf(v.x); o.y = f2bf(v.y); o.z = f2bf(v.z); o.w = f2bf(v.w);
  *(u16x4*)(out + i) = o;
}

// ---------------- generic transpose+cast: dst[c][r] = src[r][c] ----------------
__global__ __launch_bounds__(256) void k_tcast(const float* __restrict__ src,
                                               u16* __restrict__ dst, int R, int C) {
  __shared__ float tile[32][33];
  int c0 = blockIdx.x * 32, r0 = blockIdx.y * 32;
  int cx = threadIdx.x & 31, ry = threadIdx.x >> 5;
#pragma unroll
  for (int j = 0; j < 4; ++j)
    tile[ry * 4 + j][cx] = src[(long)(r0 + ry * 4 + j) * C + c0 + cx];
  __syncthreads();
#pragma unroll
  for (int j = 0; j < 4; ++j)
    dst[(long)(c0 + ry * 4 + j) * R + r0 + cx] = f2bf(tile[cx][ry * 4 + j]);
}

// ---------------- build Wcat^T [3200][1024] from W_qkv|W_z|W_b|W_a ----------------
__global__ __launch_bounds__(256) void k_wcatT(const float* __restrict__ Wqkv,
                                               const float* __restrict__ Wz,
                                               const float* __restrict__ Wb,
                                               const float* __restrict__ Wa,
                                               u16* __restrict__ dst) {
  __shared__ float tile[32][33];
  int n0 = blockIdx.x * 32, k0 = blockIdx.y * 32;
  int cx = threadIdx.x & 31, ry = threadIdx.x >> 5;
#pragma unroll
  for (int j = 0; j < 4; ++j) {
    int kk = k0 + ry * 4 + j;
    int n = n0 + cx;
    float v;
    if (n < 2048)      v = Wqkv[(long)kk * 2048 + n];
    else if (n < 3072) v = Wz[(long)kk * 1024 + (n - 2048)];
    else if (n < 3088) v = Wb[kk * 16 + (n - 3072)];
    else if (n < 3104) v = Wa[kk * 16 + (n - 3088)];
    else               v = 0.f;
    tile[ry * 4 + j][cx] = v;
  }
  __syncthreads();
#pragma unroll
  for (int j = 0; j < 4; ++j)
    dst[(long)(n0 + ry * 4 + j) * 1024 + k0 + cx] = f2bf(tile[cx][ry * 4 + j]);
}

// ---------------- bf16 MFMA GEMM: C[M,N] = A[M,K] @ Bt[N,K]^T ----------------
__global__ __launch_bounds__(256) void k_gemm(const u16* __restrict__ A,
                                              const u16* __restrict__ Bt,
                                              u16* __restrict__ C0,
                                              float* __restrict__ C1,
                                              int M, int N, int K, int mode) {
  __shared__ u16 As[128 * 64];
  __shared__ u16 Bs[128 * 64];
  int tid = threadIdx.x;
  int wid = tid >> 6, lane = tid & 63;
  int row0 = blockIdx.y * 128, col0 = blockIdx.x * 128;
  int wr = wid >> 1, wc = wid & 1;
  f32x4 acc[4][4];
#pragma unroll
  for (int m = 0; m < 4; ++m)
#pragma unroll
    for (int n = 0; n < 4; ++n) acc[m][n] = (f32x4){0.f, 0.f, 0.f, 0.f};

  int srow = lane >> 3;
  int skoff = (lane & 7) * 8;

  for (int k0 = 0; k0 < K; k0 += 64) {
#pragma unroll
    for (int it = 0; it < 4; ++it) {
      int seg = wid * 4 + it;
      int r = seg * 8 + srow;
      const u16* gA = A + (long)(row0 + r) * K + k0 + skoff;
      const u16* gB = Bt + (long)(col0 + r) * K + k0 + skoff;
      __builtin_amdgcn_global_load_lds((gptr_t)gA, (lptr_t)(As + seg * 512), 16, 0, 0);
      __builtin_amdgcn_global_load_lds((gptr_t)gB, (lptr_t)(Bs + seg * 512), 16, 0, 0);
    }
    asm volatile("s_waitcnt vmcnt(0)" ::: "memory");
    __syncthreads();
#pragma unroll
    for (int ks = 0; ks < 2; ++ks) {
      bf16x8 af[4], bfr[4];
      int kk = ks * 32 + (lane >> 4) * 8;
      int rA = wr * 64 + (lane & 15);
      int rB = wc * 64 + (lane & 15);
#pragma unroll
      for (int m = 0; m < 4; ++m) af[m] = *(const bf16x8*)(As + (rA + m * 16) * 64 + kk);
#pragma unroll
      for (int n = 0; n < 4; ++n) bfr[n] = *(const bf16x8*)(Bs + (rB + n * 16) * 64 + kk);
#pragma unroll
      for (int m = 0; m < 4; ++m)
#pragma unroll
        for (int n = 0; n < 4; ++n)
          acc[m][n] = __builtin_amdgcn_mfma_f32_16x16x32_bf16(af[m], bfr[n], acc[m][n], 0, 0, 0);
    }
    __syncthreads();
  }
#pragma unroll
  for (int m = 0; m < 4; ++m)
#pragma unroll
    for (int n = 0; n < 4; ++n)
#pragma unroll
      for (int r = 0; r < 4; ++r) {
        int row = row0 + wr * 64 + m * 16 + (lane >> 4) * 4 + r;
        int col = col0 + wc * 64 + n * 16 + (lane & 15);
        float v = acc[m][n][r];
        if (mode == 0) {
          if (col < QKVZ_) C0[(long)row * QKVZ_ + col] = f2bf(v);
          else             C1[(long)row * 128 + (col - QKVZ_)] = v;
        } else {
          C1[(long)row * N + col] = v;
        }
      }
}

// ---------------- conv(4-tap causal) + SiLU + l2norm(q,k) + beta/g ----------------
__global__ __launch_bounds__(64) void k_conv(const u16* __restrict__ qkvz,
                                             const float* __restrict__ ba,
                                             const float* __restrict__ convw,
                                             const float* __restrict__ Alog,
                                             const float* __restrict__ dtb,
                                             u16* __restrict__ qn, u16* __restrict__ kn,
                                             u16* __restrict__ vb,
                                             float* __restrict__ beta, float* __restrict__ gb) {
  int bt = blockIdx.x;
  int t = bt & 2047;
  int l = threadIdx.x;
  long rb = (long)bt * QKVZ_;
#pragma unroll 1
  for (int j = 0; j < 32; ++j) {
    int c = j * 64 + l;
    float4 w = *(const float4*)(convw + c * 4);
    float a = 0.f;
#pragma unroll
    for (int d = 0; d < 4; ++d) {
      int tt = t - 3 + d;
      float x = (tt >= 0) ? bf2f(qkvz[rb + (long)(tt - t) * QKVZ_ + c]) : 0.f;
      a += x * ((const float*)&w)[d];
    }
    float y = a * sigm(a);   // SiLU
    if (j < 16) {
      float ss = y * y;
#pragma unroll
      for (int m = 1; m < 64; m <<= 1) ss += __shfl_xor(ss, m);
      float sc = rsqrtf(ss + 1e-6f);
      if (j < 8) qn[((long)bt * 8 + j) * 64 + l] = f2bf(y * sc * 0.125f);
      else       kn[((long)bt * 8 + (j - 8)) * 64 + l] = f2bf(y * sc);
    } else {
      vb[((long)bt * 16 + (j - 16)) * 64 + l] = f2bf(y);
    }
  }
  if (l < 16) {
    float xb = ba[(long)bt * 128 + l];
    beta[bt * 16 + l] = sigm(xb);
    float xa = ba[(long)bt * 128 + 16 + l] + dtb[l];
    float sp = (xa > 20.f) ? xa : log1pf(__expf(xa));
    gb[bt * 16 + l] = -__expf(Alog[l]) * sp;
  }
}

// ---------------- chunk-parallel (MFMA): A, blocked solve, P, B, M^T, G ----------------
// LDS layout (u16 unless noted), strides chosen 16B-aligned w/ 2-way-max banks:
//   Ks[64][72], Qs[64][72] (later Ktt[64][72]), As[64][72],
//   RHSt[128][72], Xt[128][72], T4[64][32], Y[128][40]
__global__ __launch_bounds__(256) void k_cpk2(const u16* __restrict__ qn,
                                              const u16* __restrict__ kn,
                                              const u16* __restrict__ vb,
                                              const float* __restrict__ beta,
                                              const float* __restrict__ gb,
                                              float* __restrict__ Gbuf,
                                              u16* __restrict__ TKTb,
                                              u16* __restrict__ WlTb, u16* __restrict__ MTb,
                                              u16* __restrict__ Pb, u16* __restrict__ Bb) {
  int c = blockIdx.x, hv = blockIdx.y, b = blockIdx.z;
  int hk = hv >> 1;
  int bh = b * HV_ + hv;
  int tid = threadIdx.x;
  int wv = tid >> 6, lane = tid & 63;
  int frow = lane & 15, fk = (lane >> 4) * 8;   // MFMA fragment row / k-offset

  __shared__ __align__(16) char smem[78848];
  u16* Ks   = (u16*)smem;                  // [64][72]
  u16* Qs   = (u16*)(smem + 9216);         // [64][72], later Ktt
  u16* Ktt  = Qs;
  u16* As_  = (u16*)(smem + 18432);        // [64][72]
  u16* RHSt = (u16*)(smem + 27648);        // [128][72]
  u16* Xt   = (u16*)(smem + 46080);        // [128][72]
  u16* T4   = (u16*)(smem + 64512);        // [64][32]
  u16* Yl   = (u16*)(smem + 68608);        // [128][40]
  __shared__ float Gl[64];
  __shared__ float Bl[64];

  long tbase = (long)b * T_ + c * 64;
  long tile = ((long)bh * NC_ + c) * 4096;

  // ---- P1: loads, zeroing, cumsum ----
  if (tid < 64) {
    Gl[tid] = gb[(tbase + tid) * HV_ + hv];
    Bl[tid] = beta[(tbase + tid) * HV_ + hv];
  }
  if (tid == 0) {            // inclusive cumsum (wave0-local, in-order)
    float s = 0.f;
    for (int i = 0; i < 64; ++i) { s += Gl[i]; Gl[i] = s; }
  }
  if (tid < 64) Gbuf[((long)bh * NC_ + c) * 64 + tid] = Gl[tid];
  for (int e = tid; e < 4608; e += 256) ((float*)Xt)[e] = 0.f;
  for (int e = tid; e < 2560; e += 256) ((float*)Yl)[e] = 0.f;
  for (int e = tid; e < 4096; e += 256) {
    int i = e >> 6, k = e & 63;
    Ks[i * 72 + k] = kn[(tbase + i) * 512 + hk * 64 + k];
    Qs[i * 72 + k] = qn[(tbase + i) * 512 + hk * 64 + k];
  }
  __syncthreads();

  // ---- P2+P3: Dt = K@Q^T -> M^T ; D = K@K^T -> As ----
  {
    bf16x8 aKs[2];
#pragma unroll
    for (int ks = 0; ks < 2; ++ks)
      aKs[ks] = *(const bf16x8*)&Ks[(wv * 16 + frow) * 72 + ks * 32 + fk];
    f32x4 accM[4], accA[4];
#pragma unroll
    for (int nt = 0; nt < 4; ++nt) { accM[nt] = (f32x4){0,0,0,0}; accA[nt] = (f32x4){0,0,0,0}; }
#pragma unroll
    for (int ks = 0; ks < 2; ++ks) {
#pragma unroll
      for (int nt = 0; nt < 4; ++nt) {
        bf16x8 bq = *(const bf16x8*)&Qs[(nt * 16 + frow) * 72 + ks * 32 + fk];
        bf16x8 bk = *(const bf16x8*)&Ks[(nt * 16 + frow) * 72 + ks * 32 + fk];
        accM[nt] = __builtin_amdgcn_mfma_f32_16x16x32_bf16(aKs[ks], bq, accM[nt], 0, 0, 0);
        accA[nt] = __builtin_amdgcn_mfma_f32_16x16x32_bf16(aKs[ks], bk, accA[nt], 0, 0, 0);
      }
    }
    // M^T[s][i]: s = C-row, i = C-col; keep s<=i, scale exp(Gi-Gs)
#pragma unroll
    for (int nt = 0; nt < 4; ++nt) {
      int i = nt * 16 + frow;
#pragma unroll
      for (int r = 0; r < 4; ++r) {
        int s = wv * 16 + (lane >> 4) * 4 + r;
        float val = (s <= i) ? accM[nt][r] * __expf(Gl[i] - Gl[s]) : 0.f;
        MTb[tile + s * 64 + i] = f2bf(val);
      }
    }
    // A[i][s]: i = C-row, s = C-col; strict lower, scale Bl[i]*exp(Gi-Gs)
#pragma unroll
    for (int nt = 0; nt < 4; ++nt) {
      int s = nt * 16 + frow;
#pragma unroll
      for (int r = 0; r < 4; ++r) {
        int i = wv * 16 + (lane >> 4) * 4 + r;
        float val = (s < i) ? Bl[i] * __expf(Gl[i] - Gl[s]) * accA[nt][r] : 0.f;
        As_[i * 72 + s] = f2bf(val);
      }
    }
  }

  // ---- P4: RHSt[v][i] = Bl[i]*V[i][v];  RHSt[64+k][i] = Bl[i]*exp(Gi)*K[i][k] ----
  for (int e = tid; e < 4096; e += 256) {
    int i = e >> 6, v = e & 63;
    RHSt[v * 72 + i] = f2bf(Bl[i] * bf2f(vb[(tbase + i) * 1024 + hv * 64 + v]));
  }
  for (int e = tid; e < 4096; e += 256) {
    int i = e >> 6, k = e & 63;
    RHSt[(64 + k) * 72 + i] = f2bf(Bl[i] * __expf(Gl[i]) * bf2f(Ks[i * 72 + k]));
  }
  __syncthreads();   // As, RHSt, Xt-zero, Y-zero visible

  // ---- P4.5: T_bb = (I + A_bb)^-1 per wave, barrier-free ----
  {
    if (lane < 16) {
      int cc = lane;
      float Tc[16];
#pragma unroll
      for (int j = 0; j < 16; ++j) Tc[j] = (j == cc) ? 1.f : 0.f;
#pragma unroll
      for (int s = 0; s < 15; ++s)
#pragma unroll
        for (int i = s + 1; i < 16; ++i) {
          float a = bf2f(As_[(wv * 16 + i) * 72 + wv * 16 + s]);
          Tc[i] -= a * Tc[s];
        }
#pragma unroll
      for (int i = 0; i < 16; ++i) T4[(wv * 16 + i) * 32 + cc] = f2bf(Tc[i]);
    } else if (lane < 32) {
      int c2 = lane - 16;
#pragma unroll
      for (int i = 0; i < 16; ++i) T4[(wv * 16 + i) * 32 + 16 + c2] = 0;
    }
  }
  __syncthreads();   // T4 visible

  // ---- P5: blocked solve: Xt[:, b] = (RHSt[:, b] - Xt @ A[b]^T) @ T_bb^T ----
#pragma unroll 1
  for (int bb = 0; bb < 4; ++bb) {
    f32x4 uacc[2];
    uacc[0] = (f32x4){0,0,0,0}; uacc[1] = (f32x4){0,0,0,0};
#pragma unroll
    for (int ks = 0; ks < 2; ++ks) {
      bf16x8 bfr = *(const bf16x8*)&As_[(bb * 16 + frow) * 72 + ks * 32 + fk];
#pragma unroll
      for (int mt = 0; mt < 2; ++mt) {
        bf16x8 aa = *(const bf16x8*)&Xt[((wv * 2 + mt) * 16 + frow) * 72 + ks * 32 + fk];
        uacc[mt] = __builtin_amdgcn_mfma_f32_16x16x32_bf16(aa, bfr, uacc[mt], 0, 0, 0);
      }
    }
    // Y = RHSt[:, bcols] - U
#pragma unroll
    for (int mt = 0; mt < 2; ++mt)
#pragma unroll
      for (int r = 0; r < 4; ++r) {
        int vr = (wv * 2 + mt) * 16 + (lane >> 4) * 4 + r;
        float y = bf2f(RHSt[vr * 72 + bb * 16 + frow]) - uacc[mt][r];
        Yl[vr * 40 + frow] = f2bf(y);
      }
    __syncthreads();
    // Z = Y @ T_bb^T  (K=32, zero-padded)
    {
      bf16x8 tb = *(const bf16x8*)&T4[(bb * 16 + frow) * 32 + fk];
      f32x4 zacc[2];
      zacc[0] = (f32x4){0,0,0,0}; zacc[1] = (f32x4){0,0,0,0};
#pragma unroll
      for (int mt = 0; mt < 2; ++mt) {
        bf16x8 aa = *(const bf16x8*)&Yl[((wv * 2 + mt) * 16 + frow) * 40 + fk];
        zacc[mt] = __builtin_amdgcn_mfma_f32_16x16x32_bf16(aa, tb, zacc[mt], 0, 0, 0);
      }
#pragma unroll
      for (int mt = 0; mt < 2; ++mt)
#pragma unroll
        for (int r = 0; r < 4; ++r) {
          int vr = (wv * 2 + mt) * 16 + (lane >> 4) * 4 + r;
          Xt[vr * 72 + bb * 16 + frow] = f2bf(zacc[mt][r]);
        }
    }
    __syncthreads();
  }

  // ---- P6: outputs ----
  float gend = Gl[63];
  // Ktt[r][i] = exp(Gend-Gi) * K[i][r]  (into Qs region)
  for (int e = tid; e < 4096; e += 256) {
    int i = e >> 6, r = e & 63;
    Ktt[r * 72 + i] = f2bf(__expf(gend - Gl[i]) * bf2f(Ks[i * 72 + r]));
  }
  // copy Xt -> WlTb / TKTb (16-u16 segments, coalesced)
#pragma unroll
  for (int t8 = 0; t8 < 2; ++t8) {
    int seg = tid + t8 * 256;          // 0..511
    int row = seg >> 2, s4 = (seg & 3) * 16;
    bf16x8 x0 = *(const bf16x8*)&Xt[row * 72 + s4];
    bf16x8 x1 = *(const bf16x8*)&Xt[row * 72 + s4 + 8];
    u16* dst = (row < 64) ? (WlTb + tile + row * 64 + s4)
                          : (TKTb + tile + (long)(row - 64) * 64 + s4);
    *(bf16x8*)dst = x0;
    *(bf16x8*)(dst + 8) = x1;
  }
  __syncthreads();   // Ktt visible

  // B[r][v] = sum_i Ktt[r][i] * Wl[i][v] = Ktt @ Xt(v-rows)^T
  {
    f32x4 acc[4];
#pragma unroll
    for (int nt = 0; nt < 4; ++nt) acc[nt] = (f32x4){0,0,0,0};
#pragma unroll
    for (int ks = 0; ks < 2; ++ks) {
      bf16x8 aa = *(const bf16x8*)&Ktt[(wv * 16 + frow) * 72 + ks * 32 + fk];
#pragma unroll
      for (int nt = 0; nt < 4; ++nt) {
        bf16x8 bfr = *(const bf16x8*)&Xt[(nt * 16 + frow) * 72 + ks * 32 + fk];
        acc[nt] = __builtin_amdgcn_mfma_f32_16x16x32_bf16(aa, bfr, acc[nt], 0, 0, 0);
      }
    }
#pragma unroll
    for (int nt = 0; nt < 4; ++nt) {
      int v = nt * 16 + frow;
#pragma unroll
      for (int r = 0; r < 4; ++r) {
        int rr = wv * 16 + (lane >> 4) * 4 + r;
        Bb[tile + rr * 64 + v] = f2bf(acc[nt][r]);
      }
    }
  }
  // P^T[k2][r] = sum_i TK^T[k2][i] * Ktt[r][i] = Xt(64+) @ Ktt^T
  {
    f32x4 acc[4];
#pragma unroll
    for (int nt = 0; nt < 4; ++nt) acc[nt] = (f32x4){0,0,0,0};
#pragma unroll
    for (int ks = 0; ks < 2; ++ks) {
      bf16x8 aa = *(const bf16x8*)&Xt[(64 + wv * 16 + frow) * 72 + ks * 32 + fk];
#pragma unroll
      for (int nt = 0; nt < 4; ++nt) {
        bf16x8 bfr = *(const bf16x8*)&Ktt[(nt * 16 + frow) * 72 + ks * 32 + fk];
        acc[nt] = __builtin_amdgcn_mfma_f32_16x16x32_bf16(aa, bfr, acc[nt], 0, 0, 0);
      }
    }
#pragma unroll
    for (int nt = 0; nt < 4; ++nt) {
      int rr = nt * 16 + frow;
#pragma unroll
      for (int r = 0; r < 4; ++r) {
        int k2 = wv * 16 + (lane >> 4) * 4 + r;
        Pb[tile + k2 * 64 + rr] = f2bf(acc[nt][r]);
      }
    }
  }
}

// ---------------- serial scan over chunks: S' = g*S - P@S + B ----------------
__global__ __launch_bounds__(256) void k_seq2(const u16* __restrict__ Pb,
                                              const u16* __restrict__ Bb,
                                              const float* __restrict__ Gbuf,
                                              u16* __restrict__ Stb) {
  int vblk = blockIdx.x, bh = blockIdx.y;
  int tid = threadIdx.x;
  __shared__ u16 Abf[2][4096];
  __shared__ u16 Bbf[2][512];
  __shared__ float S_lds[64][10];
  __shared__ float gam[NC_];
  int i_ = tid & 63, vg = tid >> 6;    // out-row i_, v pair index vg
  int wv = tid >> 6, ln = tid & 63;
  if (tid < NC_) gam[tid] = __expf(Gbuf[((long)bh * NC_ + tid) * 64 + 63]);
  for (int e = tid; e < 640; e += 256) ((float*)S_lds)[e] = 0.f;
  float a0 = 0.f, a1 = 0.f;
  // prologue: load chunk 0
  {
    long tl = (long)bh * NC_ * 4096;
    const u16* gA = Pb + tl + wv * 512 + ln * 8;
    __builtin_amdgcn_global_load_lds((gptr_t)gA, (lptr_t)&Abf[0][wv * 512], 16, 0, 0);
    __builtin_amdgcn_global_load_lds((gptr_t)(gA + 2048), (lptr_t)&Abf[0][2048 + wv * 512], 16, 0, 0);
    int ii = tid >> 2, vp = tid & 3;
    const u16* gB = Bb + tl + ii * 64 + vblk * 8 + vp * 2;
    __builtin_amdgcn_global_load_lds((gptr_t)gB, (lptr_t)&Bbf[0][wv * 128], 4, 0, 0);
  }
  for (int c = 0; c < NC_; ++c) {
    int cur = c & 1;
    asm volatile("s_waitcnt vmcnt(0)" ::: "memory");
    __syncthreads();
    if (c + 1 < NC_) {
      long tl = ((long)bh * NC_ + c + 1) * 4096;
      const u16* gA = Pb + tl + wv * 512 + ln * 8;
      __builtin_amdgcn_global_load_lds((gptr_t)gA, (lptr_t)&Abf[cur ^ 1][wv * 512], 16, 0, 0);
      __builtin_amdgcn_global_load_lds((gptr_t)(gA + 2048), (lptr_t)&Abf[cur ^ 1][2048 + wv * 512], 16, 0, 0);
      int ii = tid >> 2, vp = tid & 3;
      const u16* gB = Bb + tl + ii * 64 + vblk * 8 + vp * 2;
      __builtin_amdgcn_global_load_lds((gptr_t)gB, (lptr_t)&Bbf[cur ^ 1][wv * 128], 4, 0, 0);
    }
    // store S_c (state entering chunk c) for k_ok2
    {
      long stile = ((long)bh * NC_ + c) * 4096;
      int v0 = vblk * 8 + vg * 2;
      Stb[stile + (long)v0 * 64 + i_] = f2bf(a0);
      Stb[stile + (long)(v0 + 1) * 64 + i_] = f2bf(a1);
    }
    float g = gam[c];
    float n0 = 0.f, n1 = 0.f;
#pragma unroll 8
    for (int k = 0; k < 64; ++k) {
      float p = bf2f(Abf[cur][k * 64 + i_]);
      float2 sv = *(const float2*)&S_lds[k][vg * 2];
      n0 += p * sv.x;
      n1 += p * sv.y;
    }
    float b0 = bf2f(Bbf[cur][i_ * 8 + vg * 2]);
    float b1 = bf2f(Bbf[cur][i_ * 8 + vg * 2 + 1]);
    a0 = g * a0 - n0 + b0;
    a1 = g * a1 - n1 + b1;
    __syncthreads();
    S_lds[i_][vg * 2] = a0;
    S_lds[i_][vg * 2 + 1] = a1;
  }
}

// ---------------- chunk-parallel outputs: W = Wl - TK@S;  O = M@W + Qt@S ----------------
__global__ __launch_bounds__(256) void k_ok2(const u16* __restrict__ MTb,
                                             const u16* __restrict__ TKTb,
                                             const u16* __restrict__ WlTb,
                                             const u16* __restrict__ Stb,
                                             const u16* __restrict__ qn,
                                             const float* __restrict__ Gbuf,
                                             float* __restrict__ O) {
  int c = blockIdx.x, hv = blockIdx.y, b = blockIdx.z;
  int bh = b * HV_ + hv, hk = hv >> 1;
  int tid = threadIdx.x;
  __shared__ float TKt[64][68];   // TK^T[k][i]; later M^T[s][i]
  __shared__ float Ss[64][68];    // S[k][v]
  __shared__ float Ws[64][68];    // Wl[i][v] -> W[i][v]
  __shared__ float Qt[64][68];    // Q^T[k][i] (scaled exp(Gi))
  __shared__ float Gl[64];
  long tile = ((long)bh * NC_ + c) * 4096;
  long tbase = (long)b * T_ + c * 64;
  if (tid < 64) Gl[tid] = Gbuf[((long)bh * NC_ + c) * 64 + tid];
  __syncthreads();
  for (int e = tid; e < 4096; e += 256)
    TKt[e >> 6][e & 63] = bf2f(TKTb[tile + e]);            // direct row copy
  for (int e = tid; e < 4096; e += 256) {
    int i = e >> 6, k = e & 63;
    Qt[k][i] = __expf(Gl[i]) * bf2f(qn[(tbase + i) * 512 + hk * 64 + k]);
  }
  for (int e = tid; e < 4096; e += 256) {
    int v = e >> 6, x = e & 63;
    Ss[x][v] = bf2f(Stb[tile + e]);                        // St[v][k] -> S[k][v]
    Ws[x][v] = bf2f(WlTb[tile + e]);                       // WlT[v][i] -> Wl[i][v]
  }
  __syncthreads();
  int tx = tid & 15, ty = tid >> 4;
  int i0 = ty * 4, v0 = tx * 4;
  // phase1: W = Wl - TK@S
  float w[4][4];
#pragma unroll
  for (int r = 0; r < 4; ++r) *(f32x4*)w[r] = *(const f32x4*)&Ws[i0 + r][v0];
  for (int k = 0; k < 64; ++k) {
    f32x4 tk = *(const f32x4*)&TKt[k][i0];
    f32x4 sv = *(const f32x4*)&Ss[k][v0];
#pragma unroll
    for (int r = 0; r < 4; ++r)
#pragma unroll
      for (int q = 0; q < 4; ++q) w[r][q] -= tk[r] * sv[q];
  }
  __syncthreads();
#pragma unroll
  for (int r = 0; r < 4; ++r) *(f32x4*)&Ws[i0 + r][v0] = *(const f32x4*)w[r];
  // load M^T[s][i] into TKt (direct row copy)
  for (int e = tid; e < 4096; e += 256)
    TKt[e >> 6][e & 63] = bf2f(MTb[tile + e]);
  __syncthreads();
  // phase2: O = M@W + Qt@S
  float o[4][4] = {};
  for (int s = 0; s < 64; ++s) {
    f32x4 mv = *(const f32x4*)&TKt[s][i0];
    f32x4 wv = *(const f32x4*)&Ws[s][v0];
#pragma unroll
    for (int r = 0; r < 4; ++r)
#pragma unroll
      for (int q = 0; q < 4; ++q) o[r][q] += mv[r] * wv[q];
  }
  for (int k = 0; k < 64; ++k) {
    f32x4 qv = *(const f32x4*)&Qt[k][i0];
    f32x4 sv = *(const f32x4*)&Ss[k][v0];
#pragma unroll
    for (int r = 0; r < 4; ++r)
#pragma unroll
      for (int q = 0; q < 4; ++q) o[r][q] += qv[r] * sv[q];
  }
#pragma unroll
  for (int r = 0; r < 4; ++r) {
    float4 o4 = make_float4(o[r][0], o[r][1], o[r][2], o[r][3]);
    *(float4*)&O[((tbase + i0 + r) * HV_ + hv) * 64 + v0] = o4;
  }
}

// ---------------- gated RMSNorm: rmsnorm(o)*w*silu(z) -> bf16 ----------------
__global__ __launch_bounds__(256) void k_rms(const float* __restrict__ O,
                                             const u16* __restrict__ qkvz,
                                             const float* __restrict__ normw,
                                             u16* __restrict__ on) {
  int bt = blockIdx.x;
  int tid = threadIdx.x;
  __shared__ float ps[256];
  __shared__ float rstd[16];
  float4 o4 = *(const float4*)&O[(long)bt * 1024 + tid * 4];
  ps[tid] = o4.x * o4.x + o4.y * o4.y + o4.z * o4.z + o4.w * o4.w;
  __syncthreads();
  if (tid < 16) {
    float s = 0.f;
#pragma unroll
    for (int u = 0; u < 16; ++u) s += ps[tid * 16 + u];
    rstd[tid] = rsqrtf(s * (1.f / 64.f) + 1e-6f);
  }
  __syncthreads();
  float rs = rstd[tid >> 4];
  u16x4 ov;
#pragma unroll
  for (int j = 0; j < 4; ++j) {
    int idx = tid * 4 + j;
    float z = bf2f(qkvz[(long)bt * QKVZ_ + 2048 + idx]);
    float val = ((const float*)&o4)[j] * rs * normw[idx & 63] * (z * sigm(z));
    ((u16*)&ov)[j] = f2bf(val);
  }
  *(u16x4*)(on + (long)bt * 1024 + tid * 4) = ov;
}

// ---------------- host launch ----------------
extern "C" void kernel_launch(void* const* d_in, const int* in_sizes, int n_in,
                              void* d_out, int out_size, void* d_ws, size_t ws_size,
                              hipStream_t stream) {
  const float* hs    = (const float*)d_in[0];
  const float* Wqkv  = (const float*)d_in[1];
  const float* Wz    = (const float*)d_in[2];
  const float* Wb    = (const float*)d_in[3];
  const float* Wa    = (const float*)d_in[4];
  const float* dtb   = (const float*)d_in[5];
  const float* Alog  = (const float*)d_in[6];
  const float* convw = (const float*)d_in[7];
  const float* normw = (const float*)d_in[8];
  const float* Wout  = (const float*)d_in[9];
  float* out = (float*)d_out;

  char* p = (char*)d_ws;
  auto take = [&](size_t bytes) {
    char* q = p;
    p += (bytes + 255) & ~(size_t)255;
    return (void*)q;
  };
  u16*   qkvz  = (u16*)take((size_t)BT_ * QKVZ_ * 2);
  float* ba    = (float*)take((size_t)BT_ * 128 * 4);
  u16*   hsb   = (u16*)take((size_t)BT_ * 1024 * 2);
  u16*   wcatT = (u16*)take((size_t)NCOL_ * 1024 * 2);
  u16*   woutT = (u16*)take((size_t)1024 * 1024 * 2);
  u16*   qn    = (u16*)take((size_t)BT_ * 512 * 2);
  u16*   kn    = (u16*)take((size_t)BT_ * 512 * 2);
  u16*   vbuf  = (u16*)take((size_t)BT_ * 1024 * 2);
  float* beta  = (float*)take((size_t)BT_ * 16 * 4);
  float* gbuf  = (float*)take((size_t)BT_ * 16 * 4);
  float* Gcum  = (float*)take((size_t)1024 * 64 * 4);
  u16*   TKTb  = (u16*)take((size_t)1024 * 4096 * 2);
  u16*   WlTb  = (u16*)take((size_t)1024 * 4096 * 2);
  u16*   MTb   = (u16*)take((size_t)1024 * 4096 * 2);
  u16*   Pb    = (u16*)take((size_t)1024 * 4096 * 2);
  u16*   Bb    = (u16*)take((size_t)1024 * 4096 * 2);
  u16*   Stb   = (u16*)take((size_t)1024 * 4096 * 2);
  float* Obuf  = (float*)take((size_t)BT_ * 1024 * 4);
  u16*   onb   = (u16*)take((size_t)BT_ * 1024 * 2);

  k_cast_hs<<<dim3(4096), dim3(256), 0, stream>>>(hs, hsb);
  k_wcatT<<<dim3(100, 32), dim3(256), 0, stream>>>(Wqkv, Wz, Wb, Wa, wcatT);
  k_tcast<<<dim3(32, 32), dim3(256), 0, stream>>>(Wout, woutT, 1024, 1024);
  k_gemm<<<dim3(25, 32), dim3(256), 0, stream>>>(hsb, wcatT, qkvz, ba, 4096, NCOL_, 1024, 0);
  k_conv<<<dim3(4096), dim3(64), 0, stream>>>(qkvz, ba, convw, Alog, dtb, qn, kn, vbuf, beta, gbuf);
  k_cpk2<<<dim3(32, 16, 2), dim3(256), 0, stream>>>(qn, kn, vbuf, beta, gbuf, Gcum, TKTb, WlTb, MTb, Pb, Bb);
  k_seq2<<<dim3(8, 32), dim3(256), 0, stream>>>(Pb, Bb, Gcum, Stb);
  k_ok2<<<dim3(32, 16, 2), dim3(256), 0, stream>>>(MTb, TKTb, WlTb, Stb, qn, Gcum, Obuf);
  k_rms<<<dim3(4096), dim3(256), 0, stream>>>(Obuf, qkvz, normw, onb);
  k_gemm<<<dim3(8, 32), dim3(256), 0, stream>>>(onb, woutT, (u16*)nullptr, out, 4096, 1024, 1024, 1);
}

// Round 6
// 357.823 us; speedup vs baseline: 1.8920x; 1.0144x over previous
//
#include <hip/hip_runtime.h>
#include <hip/hip_bf16.h>

// Qwen3.5 GatedDeltaNet forward, chunked delta-rule formulation.
// B=2,T=2048,D=1024, HV=16,HK=8,DK=DV=64, chunk=64 (32 chunks).
// Round 6: gemm1 -> 256x256 8-phase counted-vmcnt MFMA kernel (k_g1):
//          T2 st_16x32 swizzle + T3/T4 counted vmcnt(8) + T5 setprio.

typedef unsigned short u16;
typedef float f32x4 __attribute__((ext_vector_type(4)));
typedef short bf16x8 __attribute__((ext_vector_type(8)));
typedef u16 u16x4 __attribute__((ext_vector_type(4)));
typedef const __attribute__((address_space(1))) void* gptr_t;
typedef __attribute__((address_space(3))) void* lptr_t;

#define B_    2
#define T_    2048
#define HV_   16
#define HK_   8
#define NC_   32      // chunks
#define BT_   4096
#define QKVZ_ 3072
#define NPAD_ 3328    // gemm1 padded N (13 x 256)

__device__ __forceinline__ u16 f2bf(float f) {
  return __builtin_bit_cast(u16, __float2bfloat16(f));
}
__device__ __forceinline__ float bf2f(u16 u) {
  return __bfloat162float(__builtin_bit_cast(__hip_bfloat16, u));
}
__device__ __forceinline__ float sigm(float x) { return 1.f / (1.f + __expf(-x)); }

// ---------------- cast hs -> bf16 ----------------
__global__ __launch_bounds__(256) void k_cast_hs(const float* __restrict__ in,
                                                 u16* __restrict__ out) {
  int i = (blockIdx.x * 256 + threadIdx.x) * 4;
  float4 v = *(const float4*)(in + i);
  u16x4 o; o.x = f2bf(v.x); o.y = f2bf(v.y); o.z = f2bf(v.z); o.w = f2bf(v.w);
  *(u16x4*)(out + i) = o;
}

// ---------------- generic transpose+cast: dst[c][r] = src[r][c] ----------------
__global__ __launch_bounds__(256) void k_tcast(const float* __restrict__ src,
                                               u16* __restrict__ dst, int R, int C) {
  __shared__ float tile[32][33];
  int c0 = blockIdx.x * 32, r0 = blockIdx.y * 32;
  int cx = threadIdx.x & 31, ry = threadIdx.x >> 5;
#pragma unroll
  for (int j = 0; j < 4; ++j)
    tile[ry * 4 + j][cx] = src[(long)(r0 + ry * 4 + j) * C + c0 + cx];
  __syncthreads();
#pragma unroll
  for (int j = 0; j < 4; ++j)
    dst[(long)(c0 + ry * 4 + j) * R + r0 + cx] = f2bf(tile[cx][ry * 4 + j]);
}

// ---------------- build Wcat^T [3328][1024] from W_qkv|W_z|W_b|W_a ----------------
__global__ __launch_bounds__(256) void k_wcatT(const float* __restrict__ Wqkv,
                                               const float* __restrict__ Wz,
                                               const float* __restrict__ Wb,
                                               const float* __restrict__ Wa,
                                               u16* __restrict__ dst) {
  __shared__ float tile[32][33];
  int n0 = blockIdx.x * 32, k0 = blockIdx.y * 32;
  int cx = threadIdx.x & 31, ry = threadIdx.x >> 5;
#pragma unroll
  for (int j = 0; j < 4; ++j) {
    int kk = k0 + ry * 4 + j;
    int n = n0 + cx;
    float v;
    if (n < 2048)      v = Wqkv[(long)kk * 2048 + n];
    else if (n < 3072) v = Wz[(long)kk * 1024 + (n - 2048)];
    else if (n < 3088) v = Wb[kk * 16 + (n - 3072)];
    else if (n < 3104) v = Wa[kk * 16 + (n - 3088)];
    else               v = 0.f;
    tile[ry * 4 + j][cx] = v;
  }
  __syncthreads();
#pragma unroll
  for (int j = 0; j < 4; ++j)
    dst[(long)(n0 + ry * 4 + j) * 1024 + k0 + cx] = f2bf(tile[cx][ry * 4 + j]);
}

// ---------------- gemm1: 256x256 8-phase MFMA, M=4096 N=3328 K=1024 ----------------
// LDS (dynamic 128KiB): region(op,bt,ks) = 16KB, layout [256 rows][32 k] bf16,
// st_16x32 swizzle (byte ^= ((byte>>9)&1)<<5) applied via inverse-swizzled
// global source (linear global_load_lds dest) + swizzled ds_read address.
__global__ __launch_bounds__(512, 1) void k_g1(const u16* __restrict__ A,
                                               const u16* __restrict__ Bt,
                                               u16* __restrict__ C0,
                                               float* __restrict__ C1) {
  extern __shared__ u16 smem[];   // 65536 u16 = 128 KiB
  const int K = 1024;
  int tid = threadIdx.x;
  int wv = tid >> 6, lane = tid & 63;
  int wm = wv >> 2, wn = wv & 3;          // 2M x 4N waves
  int frow = lane & 15, kq = lane >> 4;
  long row0 = blockIdx.y * 256, col0 = blockIdx.x * 256;

  f32x4 acc[8][4];
#pragma unroll
  for (int m = 0; m < 8; ++m)
#pragma unroll
    for (int n = 0; n < 4; ++n) acc[m][n] = (f32x4){0.f, 0.f, 0.f, 0.f};

  // stage half (ts, js): js 0=A-ks0 1=B-ks0 2=A-ks1 3=B-ks1
  auto stage = [&](int ts, int js) {
    if (ts >= 16) return;
    int op = js & 1, ks = js >> 1;
    u16* base = smem + op * 32768 + (ts & 1) * 16384 + ks * 8192;
    const u16* gsrc = op ? Bt : A;
    long grow0 = op ? col0 : row0;
#pragma unroll
    for (int l = 0; l < 2; ++l) {
      int c = wv * 128 + l * 64 + lane;
      int cp = c ^ (((c >> 5) & 1) << 1);       // inverse st_16x32 at 16B granularity
      int r = cp >> 2, kc = (cp & 3) * 8;
      const u16* g = gsrc + (grow0 + r) * K + ts * 64 + ks * 32 + kc;
      __builtin_amdgcn_global_load_lds((gptr_t)g, (lptr_t)(base + (wv * 128 + l * 64) * 8), 16, 0, 0);
    }
  };

#define VM8 asm volatile("s_waitcnt vmcnt(8)" ::: "memory")
#define VM4 asm volatile("s_waitcnt vmcnt(4)" ::: "memory")
#define VM0 asm volatile("s_waitcnt vmcnt(0)" ::: "memory")
#define VMN

#define PHASE(T, KS, MH, STS, SJS, VMW)                                           \
  {                                                                               \
    bf16x8 af[4], bfr[4];                                                         \
    const u16* Ab = smem + ((T) & 1) * 16384 + (KS) * 8192;                       \
    const u16* Bb = smem + 32768 + ((T) & 1) * 16384 + (KS) * 8192;               \
    _Pragma("unroll") for (int mt = 0; mt < 4; ++mt) {                            \
      int R = wm * 128 + (MH) * 64 + mt * 16 + frow;                              \
      int lin = R * 64 + kq * 16;                                                 \
      af[mt] = *(const bf16x8*)((const char*)Ab + (lin ^ (((R >> 3) & 1) << 5))); \
    }                                                                             \
    _Pragma("unroll") for (int nt = 0; nt < 4; ++nt) {                            \
      int R = wn * 64 + nt * 16 + frow;                                           \
      int lin = R * 64 + kq * 16;                                                 \
      bfr[nt] = *(const bf16x8*)((const char*)Bb + (lin ^ (((R >> 3) & 1) << 5)));\
    }                                                                             \
    stage(STS, SJS);                                                              \
    VMW;                                                                          \
    __syncthreads();                                                              \
    __builtin_amdgcn_s_setprio(1);                                                \
    _Pragma("unroll") for (int mt = 0; mt < 4; ++mt)                              \
      _Pragma("unroll") for (int nt = 0; nt < 4; ++nt)                            \
        acc[(MH) * 4 + mt][nt] = __builtin_amdgcn_mfma_f32_16x16x32_bf16(         \
            af[mt], bfr[nt], acc[(MH) * 4 + mt][nt], 0, 0, 0);                    \
    __builtin_amdgcn_s_setprio(0);                                                \
    __syncthreads();                                                              \
  }

  // prologue: stage H(0,0..3), H(1,0), H(1,1); confirm H(0,0..1)
  stage(0, 0); stage(0, 1); stage(0, 2); stage(0, 3);
  stage(1, 0); stage(1, 1);
  VM8;
  __syncthreads();

#pragma unroll 1
  for (int t = 0; t < 14; ++t) {
    PHASE(t, 0, 0, t + 1, 2, VMN);
    PHASE(t, 0, 1, t + 1, 3, VM8);
    PHASE(t, 1, 0, t + 2, 0, VMN);
    PHASE(t, 1, 1, t + 2, 1, VM8);
  }
  {
    int t = 14;
    PHASE(t, 0, 0, 15, 2, VMN);
    PHASE(t, 0, 1, 15, 3, VM8);
    PHASE(t, 1, 0, 16, 0, VMN);
    PHASE(t, 1, 1, 16, 1, VM4);
  }
  {
    int t = 15;
    PHASE(t, 0, 0, 16, 2, VMN);
    PHASE(t, 0, 1, 16, 3, VM0);
    PHASE(t, 1, 0, 17, 0, VMN);
    PHASE(t, 1, 1, 17, 1, VMN);
  }
#undef PHASE

  // epilogue: col<3072 -> bf16 C0 (stride 3072); 3072..3199 -> f32 C1 (stride 128)
#pragma unroll
  for (int m = 0; m < 8; ++m)
#pragma unroll
    for (int n = 0; n < 4; ++n)
#pragma unroll
      for (int r = 0; r < 4; ++r) {
        long row = row0 + wm * 128 + m * 16 + kq * 4 + r;
        long col = col0 + wn * 64 + n * 16 + frow;
        float v = acc[m][n][r];
        if (col < QKVZ_)      C0[row * QKVZ_ + col] = f2bf(v);
        else if (col < 3200)  C1[row * 128 + (col - QKVZ_)] = v;
      }
}

// ---------------- bf16 MFMA GEMM (128^2): C1[M,N] = A[M,K] @ Bt[N,K]^T ----------------
__global__ __launch_bounds__(256) void k_gemm(const u16* __restrict__ A,
                                              const u16* __restrict__ Bt,
                                              float* __restrict__ C1,
                                              int M, int N, int K) {
  __shared__ u16 As[128 * 64];
  __shared__ u16 Bs[128 * 64];
  int tid = threadIdx.x;
  int wid = tid >> 6, lane = tid & 63;
  int row0 = blockIdx.y * 128, col0 = blockIdx.x * 128;
  int wr = wid >> 1, wc = wid & 1;
  f32x4 acc[4][4];
#pragma unroll
  for (int m = 0; m < 4; ++m)
#pragma unroll
    for (int n = 0; n < 4; ++n) acc[m][n] = (f32x4){0.f, 0.f, 0.f, 0.f};

  int srow = lane >> 3;
  int skoff = (lane & 7) * 8;

  for (int k0 = 0; k0 < K; k0 += 64) {
#pragma unroll
    for (int it = 0; it < 4; ++it) {
      int seg = wid * 4 + it;
      int r = seg * 8 + srow;
      const u16* gA = A + (long)(row0 + r) * K + k0 + skoff;
      const u16* gB = Bt + (long)(col0 + r) * K + k0 + skoff;
      __builtin_amdgcn_global_load_lds((gptr_t)gA, (lptr_t)(As + seg * 512), 16, 0, 0);
      __builtin_amdgcn_global_load_lds((gptr_t)gB, (lptr_t)(Bs + seg * 512), 16, 0, 0);
    }
    asm volatile("s_waitcnt vmcnt(0)" ::: "memory");
    __syncthreads();
#pragma unroll
    for (int ks = 0; ks < 2; ++ks) {
      bf16x8 af[4], bfr[4];
      int kk = ks * 32 + (lane >> 4) * 8;
      int rA = wr * 64 + (lane & 15);
      int rB = wc * 64 + (lane & 15);
#pragma unroll
      for (int m = 0; m < 4; ++m) af[m] = *(const bf16x8*)(As + (rA + m * 16) * 64 + kk);
#pragma unroll
      for (int n = 0; n < 4; ++n) bfr[n] = *(const bf16x8*)(Bs + (rB + n * 16) * 64 + kk);
#pragma unroll
      for (int m = 0; m < 4; ++m)
#pragma unroll
        for (int n = 0; n < 4; ++n)
          acc[m][n] = __builtin_amdgcn_mfma_f32_16x16x32_bf16(af[m], bfr[n], acc[m][n], 0, 0, 0);
    }
    __syncthreads();
  }
#pragma unroll
  for (int m = 0; m < 4; ++m)
#pragma unroll
    for (int n = 0; n < 4; ++n)
#pragma unroll
      for (int r = 0; r < 4; ++r) {
        int row = row0 + wr * 64 + m * 16 + (lane >> 4) * 4 + r;
        int col = col0 + wc * 64 + n * 16 + (lane & 15);
        C1[(long)row * N + col] = acc[m][n][r];
      }
}

// ---------------- conv(4-tap causal) + SiLU + l2norm(q,k) + beta/g ----------------
__global__ __launch_bounds__(64) void k_conv(const u16* __restrict__ qkvz,
                                             const float* __restrict__ ba,
                                             const float* __restrict__ convw,
                                             const float* __restrict__ Alog,
                                             const float* __restrict__ dtb,
                                             u16* __restrict__ qn, u16* __restrict__ kn,
                                             u16* __restrict__ vb,
                                             float* __restrict__ beta, float* __restrict__ gb) {
  int bt = blockIdx.x;
  int t = bt & 2047;
  int l = threadIdx.x;
  long rb = (long)bt * QKVZ_;
#pragma unroll 1
  for (int j = 0; j < 32; ++j) {
    int c = j * 64 + l;
    float4 w = *(const float4*)(convw + c * 4);
    float a = 0.f;
#pragma unroll
    for (int d = 0; d < 4; ++d) {
      int tt = t - 3 + d;
      float x = (tt >= 0) ? bf2f(qkvz[rb + (long)(tt - t) * QKVZ_ + c]) : 0.f;
      a += x * ((const float*)&w)[d];
    }
    float y = a * sigm(a);   // SiLU
    if (j < 16) {
      float ss = y * y;
#pragma unroll
      for (int m = 1; m < 64; m <<= 1) ss += __shfl_xor(ss, m);
      float sc = rsqrtf(ss + 1e-6f);
      if (j < 8) qn[((long)bt * 8 + j) * 64 + l] = f2bf(y * sc * 0.125f);
      else       kn[((long)bt * 8 + (j - 8)) * 64 + l] = f2bf(y * sc);
    } else {
      vb[((long)bt * 16 + (j - 16)) * 64 + l] = f2bf(y);
    }
  }
  if (l < 16) {
    float xb = ba[(long)bt * 128 + l];
    beta[bt * 16 + l] = sigm(xb);
    float xa = ba[(long)bt * 128 + 16 + l] + dtb[l];
    float sp = (xa > 20.f) ? xa : log1pf(__expf(xa));
    gb[bt * 16 + l] = -__expf(Alog[l]) * sp;
  }
}

// ---------------- chunk-parallel (MFMA): A, blocked solve, P, B, M^T, G ----------------
__global__ __launch_bounds__(256) void k_cpk2(const u16* __restrict__ qn,
                                              const u16* __restrict__ kn,
                                              const u16* __restrict__ vb,
                                              const float* __restrict__ beta,
                                              const float* __restrict__ gb,
                                              float* __restrict__ Gbuf,
                                              u16* __restrict__ TKTb,
                                              u16* __restrict__ WlTb, u16* __restrict__ MTb,
                                              u16* __restrict__ Pb, u16* __restrict__ Bb) {
  int c = blockIdx.x, hv = blockIdx.y, b = blockIdx.z;
  int hk = hv >> 1;
  int bh = b * HV_ + hv;
  int tid = threadIdx.x;
  int wv = tid >> 6, lane = tid & 63;
  int frow = lane & 15, fk = (lane >> 4) * 8;

  __shared__ __align__(16) char smem[78848];
  u16* Ks   = (u16*)smem;                  // [64][72]
  u16* Qs   = (u16*)(smem + 9216);         // [64][72], later Ktt
  u16* Ktt  = Qs;
  u16* As_  = (u16*)(smem + 18432);        // [64][72]
  u16* RHSt = (u16*)(smem + 27648);        // [128][72]
  u16* Xt   = (u16*)(smem + 46080);        // [128][72]
  u16* T4   = (u16*)(smem + 64512);        // [64][32]
  u16* Yl   = (u16*)(smem + 68608);        // [128][40]
  __shared__ float Gl[64];
  __shared__ float Bl[64];

  long tbase = (long)b * T_ + c * 64;
  long tile = ((long)bh * NC_ + c) * 4096;

  if (tid < 64) {
    Gl[tid] = gb[(tbase + tid) * HV_ + hv];
    Bl[tid] = beta[(tbase + tid) * HV_ + hv];
  }
  if (tid == 0) {
    float s = 0.f;
    for (int i = 0; i < 64; ++i) { s += Gl[i]; Gl[i] = s; }
  }
  if (tid < 64) Gbuf[((long)bh * NC_ + c) * 64 + tid] = Gl[tid];
  for (int e = tid; e < 4608; e += 256) ((float*)Xt)[e] = 0.f;
  for (int e = tid; e < 2560; e += 256) ((float*)Yl)[e] = 0.f;
  for (int e = tid; e < 4096; e += 256) {
    int i = e >> 6, k = e & 63;
    Ks[i * 72 + k] = kn[(tbase + i) * 512 + hk * 64 + k];
    Qs[i * 72 + k] = qn[(tbase + i) * 512 + hk * 64 + k];
  }
  __syncthreads();

  {
    bf16x8 aKs[2];
#pragma unroll
    for (int ks = 0; ks < 2; ++ks)
      aKs[ks] = *(const bf16x8*)&Ks[(wv * 16 + frow) * 72 + ks * 32 + fk];
    f32x4 accM[4], accA[4];
#pragma unroll
    for (int nt = 0; nt < 4; ++nt) { accM[nt] = (f32x4){0,0,0,0}; accA[nt] = (f32x4){0,0,0,0}; }
#pragma unroll
    for (int ks = 0; ks < 2; ++ks) {
#pragma unroll
      for (int nt = 0; nt < 4; ++nt) {
        bf16x8 bq = *(const bf16x8*)&Qs[(nt * 16 + frow) * 72 + ks * 32 + fk];
        bf16x8 bk = *(const bf16x8*)&Ks[(nt * 16 + frow) * 72 + ks * 32 + fk];
        accM[nt] = __builtin_amdgcn_mfma_f32_16x16x32_bf16(aKs[ks], bq, accM[nt], 0, 0, 0);
        accA[nt] = __builtin_amdgcn_mfma_f32_16x16x32_bf16(aKs[ks], bk, accA[nt], 0, 0, 0);
      }
    }
#pragma unroll
    for (int nt = 0; nt < 4; ++nt) {
      int i = nt * 16 + frow;
#pragma unroll
      for (int r = 0; r < 4; ++r) {
        int s = wv * 16 + (lane >> 4) * 4 + r;
        float val = (s <= i) ? accM[nt][r] * __expf(Gl[i] - Gl[s]) : 0.f;
        MTb[tile + s * 64 + i] = f2bf(val);
      }
    }
#pragma unroll
    for (int nt = 0; nt < 4; ++nt) {
      int s = nt * 16 + frow;
#pragma unroll
      for (int r = 0; r < 4; ++r) {
        int i = wv * 16 + (lane >> 4) * 4 + r;
        float val = (s < i) ? Bl[i] * __expf(Gl[i] - Gl[s]) * accA[nt][r] : 0.f;
        As_[i * 72 + s] = f2bf(val);
      }
    }
  }

  for (int e = tid; e < 4096; e += 256) {
    int i = e >> 6, v = e & 63;
    RHSt[v * 72 + i] = f2bf(Bl[i] * bf2f(vb[(tbase + i) * 1024 + hv * 64 + v]));
  }
  for (int e = tid; e < 4096; e += 256) {
    int i = e >> 6, k = e & 63;
    RHSt[(64 + k) * 72 + i] = f2bf(Bl[i] * __expf(Gl[i]) * bf2f(Ks[i * 72 + k]));
  }
  __syncthreads();

  {
    if (lane < 16) {
      int cc = lane;
      float Tc[16];
#pragma unroll
      for (int j = 0; j < 16; ++j) Tc[j] = (j == cc) ? 1.f : 0.f;
#pragma unroll
      for (int s = 0; s < 15; ++s)
#pragma unroll
        for (int i = s + 1; i < 16; ++i) {
          float a = bf2f(As_[(wv * 16 + i) * 72 + wv * 16 + s]);
          Tc[i] -= a * Tc[s];
        }
#pragma unroll
      for (int i = 0; i < 16; ++i) T4[(wv * 16 + i) * 32 + cc] = f2bf(Tc[i]);
    } else if (lane < 32) {
      int c2 = lane - 16;
#pragma unroll
      for (int i = 0; i < 16; ++i) T4[(wv * 16 + i) * 32 + 16 + c2] = 0;
    }
  }
  __syncthreads();

#pragma unroll 1
  for (int bb = 0; bb < 4; ++bb) {
    f32x4 uacc[2];
    uacc[0] = (f32x4){0,0,0,0}; uacc[1] = (f32x4){0,0,0,0};
#pragma unroll
    for (int ks = 0; ks < 2; ++ks) {
      bf16x8 bfr = *(const bf16x8*)&As_[(bb * 16 + frow) * 72 + ks * 32 + fk];
#pragma unroll
      for (int mt = 0; mt < 2; ++mt) {
        bf16x8 aa = *(const bf16x8*)&Xt[((wv * 2 + mt) * 16 + frow) * 72 + ks * 32 + fk];
        uacc[mt] = __builtin_amdgcn_mfma_f32_16x16x32_bf16(aa, bfr, uacc[mt], 0, 0, 0);
      }
    }
#pragma unroll
    for (int mt = 0; mt < 2; ++mt)
#pragma unroll
      for (int r = 0; r < 4; ++r) {
        int vr = (wv * 2 + mt) * 16 + (lane >> 4) * 4 + r;
        float y = bf2f(RHSt[vr * 72 + bb * 16 + frow]) - uacc[mt][r];
        Yl[vr * 40 + frow] = f2bf(y);
      }
    __syncthreads();
    {
      bf16x8 tb = *(const bf16x8*)&T4[(bb * 16 + frow) * 32 + fk];
      f32x4 zacc[2];
      zacc[0] = (f32x4){0,0,0,0}; zacc[1] = (f32x4){0,0,0,0};
#pragma unroll
      for (int mt = 0; mt < 2; ++mt) {
        bf16x8 aa = *(const bf16x8*)&Yl[((wv * 2 + mt) * 16 + frow) * 40 + fk];
        zacc[mt] = __builtin_amdgcn_mfma_f32_16x16x32_bf16(aa, tb, zacc[mt], 0, 0, 0);
      }
#pragma unroll
      for (int mt = 0; mt < 2; ++mt)
#pragma unroll
        for (int r = 0; r < 4; ++r) {
          int vr = (wv * 2 + mt) * 16 + (lane >> 4) * 4 + r;
          Xt[vr * 72 + bb * 16 + frow] = f2bf(zacc[mt][r]);
        }
    }
    __syncthreads();
  }

  float gend = Gl[63];
  for (int e = tid; e < 4096; e += 256) {
    int i = e >> 6, r = e & 63;
    Ktt[r * 72 + i] = f2bf(__expf(gend - Gl[i]) * bf2f(Ks[i * 72 + r]));
  }
#pragma unroll
  for (int t8 = 0; t8 < 2; ++t8) {
    int seg = tid + t8 * 256;
    int row = seg >> 2, s4 = (seg & 3) * 16;
    bf16x8 x0 = *(const bf16x8*)&Xt[row * 72 + s4];
    bf16x8 x1 = *(const bf16x8*)&Xt[row * 72 + s4 + 8];
    u16* dst = (row < 64) ? (WlTb + tile + row * 64 + s4)
                          : (TKTb + tile + (long)(row - 64) * 64 + s4);
    *(bf16x8*)dst = x0;
    *(bf16x8*)(dst + 8) = x1;
  }
  __syncthreads();

  {
    f32x4 acc[4];
#pragma unroll
    for (int nt = 0; nt < 4; ++nt) acc[nt] = (f32x4){0,0,0,0};
#pragma unroll
    for (int ks = 0; ks < 2; ++ks) {
      bf16x8 aa = *(const bf16x8*)&Ktt[(wv * 16 + frow) * 72 + ks * 32 + fk];
#pragma unroll
      for (int nt = 0; nt < 4; ++nt) {
        bf16x8 bfr = *(const bf16x8*)&Xt[(nt * 16 + frow) * 72 + ks * 32 + fk];
        acc[nt] = __builtin_amdgcn_mfma_f32_16x16x32_bf16(aa, bfr, acc[nt], 0, 0, 0);
      }
    }
#pragma unroll
    for (int nt = 0; nt < 4; ++nt) {
      int v = nt * 16 + frow;
#pragma unroll
      for (int r = 0; r < 4; ++r) {
        int rr = wv * 16 + (lane >> 4) * 4 + r;
        Bb[tile + rr * 64 + v] = f2bf(acc[nt][r]);
      }
    }
  }
  {
    f32x4 acc[4];
#pragma unroll
    for (int nt = 0; nt < 4; ++nt) acc[nt] = (f32x4){0,0,0,0};
#pragma unroll
    for (int ks = 0; ks < 2; ++ks) {
      bf16x8 aa = *(const bf16x8*)&Xt[(64 + wv * 16 + frow) * 72 + ks * 32 + fk];
#pragma unroll
      for (int nt = 0; nt < 4; ++nt) {
        bf16x8 bfr = *(const bf16x8*)&Ktt[(nt * 16 + frow) * 72 + ks * 32 + fk];
        acc[nt] = __builtin_amdgcn_mfma_f32_16x16x32_bf16(aa, bfr, acc[nt], 0, 0, 0);
      }
    }
#pragma unroll
    for (int nt = 0; nt < 4; ++nt) {
      int rr = nt * 16 + frow;
#pragma unroll
      for (int r = 0; r < 4; ++r) {
        int k2 = wv * 16 + (lane >> 4) * 4 + r;
        Pb[tile + k2 * 64 + rr] = f2bf(acc[nt][r]);
      }
    }
  }
}

// ---------------- serial scan over chunks: S' = g*S - P@S + B ----------------
__global__ __launch_bounds__(256) void k_seq2(const u16* __restrict__ Pb,
                                              const u16* __restrict__ Bb,
                                              const float* __restrict__ Gbuf,
                                              u16* __restrict__ Stb) {
  int vblk = blockIdx.x, bh = blockIdx.y;
  int tid = threadIdx.x;
  __shared__ u16 Abf[2][4096];
  __shared__ u16 Bbf[2][512];
  __shared__ float S_lds[64][10];
  __shared__ float gam[NC_];
  int i_ = tid & 63, vg = tid >> 6;
  int wv = tid >> 6, ln = tid & 63;
  if (tid < NC_) gam[tid] = __expf(Gbuf[((long)bh * NC_ + tid) * 64 + 63]);
  for (int e = tid; e < 640; e += 256) ((float*)S_lds)[e] = 0.f;
  float a0 = 0.f, a1 = 0.f;
  {
    long tl = (long)bh * NC_ * 4096;
    const u16* gA = Pb + tl + wv * 512 + ln * 8;
    __builtin_amdgcn_global_load_lds((gptr_t)gA, (lptr_t)&Abf[0][wv * 512], 16, 0, 0);
    __builtin_amdgcn_global_load_lds((gptr_t)(gA + 2048), (lptr_t)&Abf[0][2048 + wv * 512], 16, 0, 0);
    int ii = tid >> 2, vp = tid & 3;
    const u16* gB = Bb + tl + ii * 64 + vblk * 8 + vp * 2;
    __builtin_amdgcn_global_load_lds((gptr_t)gB, (lptr_t)&Bbf[0][wv * 128], 4, 0, 0);
  }
  for (int c = 0; c < NC_; ++c) {
    int cur = c & 1;
    asm volatile("s_waitcnt vmcnt(0)" ::: "memory");
    __syncthreads();
    if (c + 1 < NC_) {
      long tl = ((long)bh * NC_ + c + 1) * 4096;
      const u16* gA = Pb + tl + wv * 512 + ln * 8;
      __builtin_amdgcn_global_load_lds((gptr_t)gA, (lptr_t)&Abf[cur ^ 1][wv * 512], 16, 0, 0);
      __builtin_amdgcn_global_load_lds((gptr_t)(gA + 2048), (lptr_t)&Abf[cur ^ 1][2048 + wv * 512], 16, 0, 0);
      int ii = tid >> 2, vp = tid & 3;
      const u16* gB = Bb + tl + ii * 64 + vblk * 8 + vp * 2;
      __builtin_amdgcn_global_load_lds((gptr_t)gB, (lptr_t)&Bbf[cur ^ 1][wv * 128], 4, 0, 0);
    }
    {
      long stile = ((long)bh * NC_ + c) * 4096;
      int v0 = vblk * 8 + vg * 2;
      Stb[stile + (long)v0 * 64 + i_] = f2bf(a0);
      Stb[stile + (long)(v0 + 1) * 64 + i_] = f2bf(a1);
    }
    float g = gam[c];
    float n0 = 0.f, n1 = 0.f;
#pragma unroll 8
    for (int k = 0; k < 64; ++k) {
      float p = bf2f(Abf[cur][k * 64 + i_]);
      float2 sv = *(const float2*)&S_lds[k][vg * 2];
      n0 += p * sv.x;
      n1 += p * sv.y;
    }
    float b0 = bf2f(Bbf[cur][i_ * 8 + vg * 2]);
    float b1 = bf2f(Bbf[cur][i_ * 8 + vg * 2 + 1]);
    a0 = g * a0 - n0 + b0;
    a1 = g * a1 - n1 + b1;
    __syncthreads();
    S_lds[i_][vg * 2] = a0;
    S_lds[i_][vg * 2 + 1] = a1;
  }
}

// ---------------- chunk-parallel outputs: W = Wl - TK@S;  O = M@W + Qt@S ----------------
__global__ __launch_bounds__(256) void k_ok2(const u16* __restrict__ MTb,
                                             const u16* __restrict__ TKTb,
                                             const u16* __restrict__ WlTb,
                                             const u16* __restrict__ Stb,
                                             const u16* __restrict__ qn,
                                             const float* __restrict__ Gbuf,
                                             float* __restrict__ O) {
  int c = blockIdx.x, hv = blockIdx.y, b = blockIdx.z;
  int bh = b * HV_ + hv, hk = hv >> 1;
  int tid = threadIdx.x;
  __shared__ float TKt[64][68];
  __shared__ float Ss[64][68];
  __shared__ float Ws[64][68];
  __shared__ float Qt[64][68];
  __shared__ float Gl[64];
  long tile = ((long)bh * NC_ + c) * 4096;
  long tbase = (long)b * T_ + c * 64;
  if (tid < 64) Gl[tid] = Gbuf[((long)bh * NC_ + c) * 64 + tid];
  __syncthreads();
  for (int e = tid; e < 4096; e += 256)
    TKt[e >> 6][e & 63] = bf2f(TKTb[tile + e]);
  for (int e = tid; e < 4096; e += 256) {
    int i = e >> 6, k = e & 63;
    Qt[k][i] = __expf(Gl[i]) * bf2f(qn[(tbase + i) * 512 + hk * 64 + k]);
  }
  for (int e = tid; e < 4096; e += 256) {
    int v = e >> 6, x = e & 63;
    Ss[x][v] = bf2f(Stb[tile + e]);
    Ws[x][v] = bf2f(WlTb[tile + e]);
  }
  __syncthreads();
  int tx = tid & 15, ty = tid >> 4;
  int i0 = ty * 4, v0 = tx * 4;
  float w[4][4];
#pragma unroll
  for (int r = 0; r < 4; ++r) *(f32x4*)w[r] = *(const f32x4*)&Ws[i0 + r][v0];
  for (int k = 0; k < 64; ++k) {
    f32x4 tk = *(const f32x4*)&TKt[k][i0];
    f32x4 sv = *(const f32x4*)&Ss[k][v0];
#pragma unroll
    for (int r = 0; r < 4; ++r)
#pragma unroll
      for (int q = 0; q < 4; ++q) w[r][q] -= tk[r] * sv[q];
  }
  __syncthreads();
#pragma unroll
  for (int r = 0; r < 4; ++r) *(f32x4*)&Ws[i0 + r][v0] = *(const f32x4*)w[r];
  for (int e = tid; e < 4096; e += 256)
    TKt[e >> 6][e & 63] = bf2f(MTb[tile + e]);
  __syncthreads();
  float o[4][4] = {};
  for (int s = 0; s < 64; ++s) {
    f32x4 mv = *(const f32x4*)&TKt[s][i0];
    f32x4 wv = *(const f32x4*)&Ws[s][v0];
#pragma unroll
    for (int r = 0; r < 4; ++r)
#pragma unroll
      for (int q = 0; q < 4; ++q) o[r][q] += mv[r] * wv[q];
  }
  for (int k = 0; k < 64; ++k) {
    f32x4 qv = *(const f32x4*)&Qt[k][i0];
    f32x4 sv = *(const f32x4*)&Ss[k][v0];
#pragma unroll
    for (int r = 0; r < 4; ++r)
#pragma unroll
      for (int q = 0; q < 4; ++q) o[r][q] += qv[r] * sv[q];
  }
#pragma unroll
  for (int r = 0; r < 4; ++r) {
    float4 o4 = make_float4(o[r][0], o[r][1], o[r][2], o[r][3]);
    *(float4*)&O[((tbase + i0 + r) * HV_ + hv) * 64 + v0] = o4;
  }
}

// ---------------- gated RMSNorm: rmsnorm(o)*w*silu(z) -> bf16 ----------------
__global__ __launch_bounds__(256) void k_rms(const float* __restrict__ O,
                                             const u16* __restrict__ qkvz,
                                             const float* __restrict__ normw,
                                             u16* __restrict__ on) {
  int bt = blockIdx.x;
  int tid = threadIdx.x;
  __shared__ float ps[256];
  __shared__ float rstd[16];
  float4 o4 = *(const float4*)&O[(long)bt * 1024 + tid * 4];
  ps[tid] = o4.x * o4.x + o4.y * o4.y + o4.z * o4.z + o4.w * o4.w;
  __syncthreads();
  if (tid < 16) {
    float s = 0.f;
#pragma unroll
    for (int u = 0; u < 16; ++u) s += ps[tid * 16 + u];
    rstd[tid] = rsqrtf(s * (1.f / 64.f) + 1e-6f);
  }
  __syncthreads();
  float rs = rstd[tid >> 4];
  u16x4 ov;
#pragma unroll
  for (int j = 0; j < 4; ++j) {
    int idx = tid * 4 + j;
    float z = bf2f(qkvz[(long)bt * QKVZ_ + 2048 + idx]);
    float val = ((const float*)&o4)[j] * rs * normw[idx & 63] * (z * sigm(z));
    ((u16*)&ov)[j] = f2bf(val);
  }
  *(u16x4*)(on + (long)bt * 1024 + tid * 4) = ov;
}

// ---------------- host launch ----------------
extern "C" void kernel_launch(void* const* d_in, const int* in_sizes, int n_in,
                              void* d_out, int out_size, void* d_ws, size_t ws_size,
                              hipStream_t stream) {
  const float* hs    = (const float*)d_in[0];
  const float* Wqkv  = (const float*)d_in[1];
  const float* Wz    = (const float*)d_in[2];
  const float* Wb    = (const float*)d_in[3];
  const float* Wa    = (const float*)d_in[4];
  const float* dtb   = (const float*)d_in[5];
  const float* Alog  = (const float*)d_in[6];
  const float* convw = (const float*)d_in[7];
  const float* normw = (const float*)d_in[8];
  const float* Wout  = (const float*)d_in[9];
  float* out = (float*)d_out;

  char* p = (char*)d_ws;
  auto take = [&](size_t bytes) {
    char* q = p;
    p += (bytes + 255) & ~(size_t)255;
    return (void*)q;
  };
  u16*   qkvz  = (u16*)take((size_t)BT_ * QKVZ_ * 2);
  float* ba    = (float*)take((size_t)BT_ * 128 * 4);
  u16*   hsb   = (u16*)take((size_t)BT_ * 1024 * 2);
  u16*   wcatT = (u16*)take((size_t)NPAD_ * 1024 * 2);
  u16*   woutT = (u16*)take((size_t)1024 * 1024 * 2);
  u16*   qn    = (u16*)take((size_t)BT_ * 512 * 2);
  u16*   kn    = (u16*)take((size_t)BT_ * 512 * 2);
  u16*   vbuf  = (u16*)take((size_t)BT_ * 1024 * 2);
  float* beta  = (float*)take((size_t)BT_ * 16 * 4);
  float* gbuf  = (float*)take((size_t)BT_ * 16 * 4);
  float* Gcum  = (float*)take((size_t)1024 * 64 * 4);
  u16*   TKTb  = (u16*)take((size_t)1024 * 4096 * 2);
  u16*   WlTb  = (u16*)take((size_t)1024 * 4096 * 2);
  u16*   MTb   = (u16*)take((size_t)1024 * 4096 * 2);
  u16*   Pb    = (u16*)take((size_t)1024 * 4096 * 2);
  u16*   Bb    = (u16*)take((size_t)1024 * 4096 * 2);
  u16*   Stb   = (u16*)take((size_t)1024 * 4096 * 2);
  float* Obuf  = (float*)take((size_t)BT_ * 1024 * 4);
  u16*   onb   = (u16*)take((size_t)BT_ * 1024 * 2);

  k_cast_hs<<<dim3(4096), dim3(256), 0, stream>>>(hs, hsb);
  k_wcatT<<<dim3(104, 32), dim3(256), 0, stream>>>(Wqkv, Wz, Wb, Wa, wcatT);
  k_tcast<<<dim3(32, 32), dim3(256), 0, stream>>>(Wout, woutT, 1024, 1024);
  k_g1<<<dim3(13, 16), dim3(512), 131072, stream>>>(hsb, wcatT, qkvz, ba);
  k_conv<<<dim3(4096), dim3(64), 0, stream>>>(qkvz, ba, convw, Alog, dtb, qn, kn, vbuf, beta, gbuf);
  k_cpk2<<<dim3(32, 16, 2), dim3(256), 0, stream>>>(qn, kn, vbuf, beta, gbuf, Gcum, TKTb, WlTb, MTb, Pb, Bb);
  k_seq2<<<dim3(8, 32), dim3(256), 0, stream>>>(Pb, Bb, Gcum, Stb);
  k_ok2<<<dim3(32, 16, 2), dim3(256), 0, stream>>>(MTb, TKTb, WlTb, Stb, qn, Gcum, Obuf);
  k_rms<<<dim3(4096), dim3(256), 0, stream>>>(Obuf, qkvz, normw, onb);
  k_gemm<<<dim3(8, 32), dim3(256), 0, stream>>>(onb, woutT, out, 4096, 1024, 1024);
}

// Round 7
// 291.874 us; speedup vs baseline: 2.3195x; 1.2259x over previous
//
#include <hip/hip_runtime.h>
#include <hip/hip_bf16.h>

// Qwen3.5 GatedDeltaNet forward, chunked delta-rule formulation.
// Round 7: k_g1 -> 32-section ring-4 single-barrier schedule (prefetch 3 sections);
//          k_ok3 MFMA-ized (M, TK made row-major in k_cpk2); k_conv vectorized.

typedef unsigned short u16;
typedef float f32x4 __attribute__((ext_vector_type(4)));
typedef short bf16x8 __attribute__((ext_vector_type(8)));
typedef u16 u16x4 __attribute__((ext_vector_type(4)));
typedef const __attribute__((address_space(1))) void* gptr_t;
typedef __attribute__((address_space(3))) void* lptr_t;

#define B_    2
#define T_    2048
#define HV_   16
#define HK_   8
#define NC_   32
#define BT_   4096
#define QKVZ_ 3072
#define NPAD_ 3328

__device__ __forceinline__ u16 f2bf(float f) {
  return __builtin_bit_cast(u16, __float2bfloat16(f));
}
__device__ __forceinline__ float bf2f(u16 u) {
  return __bfloat162float(__builtin_bit_cast(__hip_bfloat16, u));
}
__device__ __forceinline__ float sigm(float x) { return 1.f / (1.f + __expf(-x)); }

// ---------------- cast hs -> bf16 ----------------
__global__ __launch_bounds__(256) void k_cast_hs(const float* __restrict__ in,
                                                 u16* __restrict__ out) {
  int i = (blockIdx.x * 256 + threadIdx.x) * 4;
  float4 v = *(const float4*)(in + i);
  u16x4 o; o.x = f2bf(v.x); o.y = f2bf(v.y); o.z = f2bf(v.z); o.w = f2bf(v.w);
  *(u16x4*)(out + i) = o;
}

// ---------------- generic transpose+cast ----------------
__global__ __launch_bounds__(256) void k_tcast(const float* __restrict__ src,
                                               u16* __restrict__ dst, int R, int C) {
  __shared__ float tile[32][33];
  int c0 = blockIdx.x * 32, r0 = blockIdx.y * 32;
  int cx = threadIdx.x & 31, ry = threadIdx.x >> 5;
#pragma unroll
  for (int j = 0; j < 4; ++j)
    tile[ry * 4 + j][cx] = src[(long)(r0 + ry * 4 + j) * C + c0 + cx];
  __syncthreads();
#pragma unroll
  for (int j = 0; j < 4; ++j)
    dst[(long)(c0 + ry * 4 + j) * R + r0 + cx] = f2bf(tile[cx][ry * 4 + j]);
}

// ---------------- build Wcat^T [3328][1024] ----------------
__global__ __launch_bounds__(256) void k_wcatT(const float* __restrict__ Wqkv,
                                               const float* __restrict__ Wz,
                                               const float* __restrict__ Wb,
                                               const float* __restrict__ Wa,
                                               u16* __restrict__ dst) {
  __shared__ float tile[32][33];
  int n0 = blockIdx.x * 32, k0 = blockIdx.y * 32;
  int cx = threadIdx.x & 31, ry = threadIdx.x >> 5;
#pragma unroll
  for (int j = 0; j < 4; ++j) {
    int kk = k0 + ry * 4 + j;
    int n = n0 + cx;
    float v;
    if (n < 2048)      v = Wqkv[(long)kk * 2048 + n];
    else if (n < 3072) v = Wz[(long)kk * 1024 + (n - 2048)];
    else if (n < 3088) v = Wb[kk * 16 + (n - 3072)];
    else if (n < 3104) v = Wa[kk * 16 + (n - 3088)];
    else               v = 0.f;
    tile[ry * 4 + j][cx] = v;
  }
  __syncthreads();
#pragma unroll
  for (int j = 0; j < 4; ++j)
    dst[(long)(n0 + ry * 4 + j) * 1024 + k0 + cx] = f2bf(tile[cx][ry * 4 + j]);
}

// ---------------- gemm1: 256x256, 32-k sections, ring-4, 1 barrier/section ----------
// Slot layout [256 rows][32 k] bf16 (64B rows); chunk-rotate swizzle
// chunk' = (kc + (r>>1)) & 3, applied via pre-permuted global source.
__global__ __launch_bounds__(512, 1) void k_g1(const u16* __restrict__ A,
                                               const u16* __restrict__ Bt,
                                               u16* __restrict__ C0,
                                               float* __restrict__ C1) {
  extern __shared__ u16 smem[];   // 128 KiB: A slots [0,64K), B slots [64K,128K)
  const int K = 1024;
  int tid = threadIdx.x;
  int wv = tid >> 6, lane = tid & 63;
  int wm = wv >> 2, wn = wv & 3;          // 2M x 4N waves
  int frow = lane & 15, kq = lane >> 4;
  long row0 = blockIdx.y * 256, col0 = blockIdx.x * 256;

  f32x4 acc[8][4];
#pragma unroll
  for (int m = 0; m < 8; ++m)
#pragma unroll
    for (int n = 0; n < 4; ++n) acc[m][n] = (f32x4){0.f, 0.f, 0.f, 0.f};

  int lr = lane >> 2;                      // row within 16-row seg
  int kc_src = ((lane & 3) - (lane >> 3)) & 3;  // pre-permuted source chunk

  auto stage = [&](int ts) {               // stage section ts for both ops
#pragma unroll
    for (int op = 0; op < 2; ++op) {
      u16* base = smem + op * 32768 + (ts & 3) * 8192;
      const u16* gsrc = op ? Bt : A;
      long grow0 = op ? col0 : row0;
#pragma unroll
      for (int it = 0; it < 2; ++it) {
        int seg = wv * 2 + it;             // 16 segs x 16 rows
        const u16* g = gsrc + (grow0 + seg * 16 + lr) * K + ts * 32 + kc_src * 8;
        __builtin_amdgcn_global_load_lds((gptr_t)g, (lptr_t)(base + seg * 512), 16, 0, 0);
      }
    }
  };

  auto section = [&](int h) {
    const char* Ab = (const char*)(smem + (h & 3) * 8192);
    const char* Bb = (const char*)(smem + 32768 + (h & 3) * 8192);
    bf16x8 af[8], bfr[4];
#pragma unroll
    for (int mt = 0; mt < 8; ++mt) {
      int R = wm * 128 + mt * 16 + frow;
      af[mt] = *(const bf16x8*)(Ab + R * 64 + (((kq + (R >> 1)) & 3) << 4));
    }
#pragma unroll
    for (int nt = 0; nt < 4; ++nt) {
      int R = wn * 64 + nt * 16 + frow;
      bfr[nt] = *(const bf16x8*)(Bb + R * 64 + (((kq + (R >> 1)) & 3) << 4));
    }
    __builtin_amdgcn_s_setprio(1);
#pragma unroll
    for (int mt = 0; mt < 8; ++mt)
#pragma unroll
      for (int nt = 0; nt < 4; ++nt)
        acc[mt][nt] = __builtin_amdgcn_mfma_f32_16x16x32_bf16(af[mt], bfr[nt], acc[mt][nt], 0, 0, 0);
    __builtin_amdgcn_s_setprio(0);
  };

  stage(0); stage(1); stage(2);
#pragma unroll 1
  for (int h = 0; h < 29; ++h) {
    asm volatile("s_waitcnt vmcnt(8)" ::: "memory");
    __syncthreads();
    stage(h + 3);
    section(h);
  }
  asm volatile("s_waitcnt vmcnt(8)" ::: "memory");
  __syncthreads();
  section(29);
  asm volatile("s_waitcnt vmcnt(4)" ::: "memory");
  __syncthreads();
  section(30);
  asm volatile("s_waitcnt vmcnt(0)" ::: "memory");
  __syncthreads();
  section(31);

  // epilogue: col<3072 -> bf16 C0; 3072..3199 -> f32 C1 (stride 128)
#pragma unroll
  for (int m = 0; m < 8; ++m)
#pragma unroll
    for (int n = 0; n < 4; ++n)
#pragma unroll
      for (int r = 0; r < 4; ++r) {
        long row = row0 + wm * 128 + m * 16 + kq * 4 + r;
        long col = col0 + wn * 64 + n * 16 + frow;
        float v = acc[m][n][r];
        if (col < QKVZ_)      C0[row * QKVZ_ + col] = f2bf(v);
        else if (col < 3200)  C1[row * 128 + (col - QKVZ_)] = v;
      }
}

// ---------------- bf16 MFMA GEMM (128^2): out-proj ----------------
__global__ __launch_bounds__(256) void k_gemm(const u16* __restrict__ A,
                                              const u16* __restrict__ Bt,
                                              float* __restrict__ C1,
                                              int M, int N, int K) {
  __shared__ u16 As[128 * 64];
  __shared__ u16 Bs[128 * 64];
  int tid = threadIdx.x;
  int wid = tid >> 6, lane = tid & 63;
  int row0 = blockIdx.y * 128, col0 = blockIdx.x * 128;
  int wr = wid >> 1, wc = wid & 1;
  f32x4 acc[4][4];
#pragma unroll
  for (int m = 0; m < 4; ++m)
#pragma unroll
    for (int n = 0; n < 4; ++n) acc[m][n] = (f32x4){0.f, 0.f, 0.f, 0.f};
  int srow = lane >> 3;
  int skoff = (lane & 7) * 8;
  for (int k0 = 0; k0 < K; k0 += 64) {
#pragma unroll
    for (int it = 0; it < 4; ++it) {
      int seg = wid * 4 + it;
      int r = seg * 8 + srow;
      const u16* gA = A + (long)(row0 + r) * K + k0 + skoff;
      const u16* gB = Bt + (long)(col0 + r) * K + k0 + skoff;
      __builtin_amdgcn_global_load_lds((gptr_t)gA, (lptr_t)(As + seg * 512), 16, 0, 0);
      __builtin_amdgcn_global_load_lds((gptr_t)gB, (lptr_t)(Bs + seg * 512), 16, 0, 0);
    }
    asm volatile("s_waitcnt vmcnt(0)" ::: "memory");
    __syncthreads();
#pragma unroll
    for (int ks = 0; ks < 2; ++ks) {
      bf16x8 af[4], bfr[4];
      int kk = ks * 32 + (lane >> 4) * 8;
      int rA = wr * 64 + (lane & 15);
      int rB = wc * 64 + (lane & 15);
#pragma unroll
      for (int m = 0; m < 4; ++m) af[m] = *(const bf16x8*)(As + (rA + m * 16) * 64 + kk);
#pragma unroll
      for (int n = 0; n < 4; ++n) bfr[n] = *(const bf16x8*)(Bs + (rB + n * 16) * 64 + kk);
#pragma unroll
      for (int m = 0; m < 4; ++m)
#pragma unroll
        for (int n = 0; n < 4; ++n)
          acc[m][n] = __builtin_amdgcn_mfma_f32_16x16x32_bf16(af[m], bfr[n], acc[m][n], 0, 0, 0);
    }
    __syncthreads();
  }
#pragma unroll
  for (int m = 0; m < 4; ++m)
#pragma unroll
    for (int n = 0; n < 4; ++n)
#pragma unroll
      for (int r = 0; r < 4; ++r) {
        int row = row0 + wr * 64 + m * 16 + (lane >> 4) * 4 + r;
        int col = col0 + wc * 64 + n * 16 + (lane & 15);
        C1[(long)row * N + col] = acc[m][n][r];
      }
}

// ---------------- conv(4-tap causal) + SiLU + l2norm(q,k) + beta/g, vectorized ----
__global__ __launch_bounds__(256) void k_conv(const u16* __restrict__ qkvz,
                                              const float* __restrict__ ba,
                                              const float* __restrict__ convw,
                                              const float* __restrict__ Alog,
                                              const float* __restrict__ dtb,
                                              u16* __restrict__ qn, u16* __restrict__ kn,
                                              u16* __restrict__ vb,
                                              float* __restrict__ beta, float* __restrict__ gb) {
  int bt = blockIdx.x;
  int t = bt & 2047;
  int g = threadIdx.x;          // 8-channel group, c = g*8 in [0,2048)
  int c = g * 8;
  long rb = (long)bt * QKVZ_;
  bf16x8 x[4];
#pragma unroll
  for (int d = 0; d < 4; ++d) {
    int tt = t - 3 + d;
    if (tt >= 0) x[d] = *(const bf16x8*)(qkvz + rb + (long)(d - 3) * QKVZ_ + c);
    else         x[d] = (bf16x8){0, 0, 0, 0, 0, 0, 0, 0};
  }
  float y[8];
#pragma unroll
  for (int j = 0; j < 8; ++j) {
    float4 w4 = *(const float4*)(convw + (c + j) * 4);
    float a = 0.f;
#pragma unroll
    for (int d = 0; d < 4; ++d) {
      int tt = t - 3 + d;
      float xv = (tt >= 0) ? bf2f((u16)x[d][j]) : 0.f;
      a += xv * ((const float*)&w4)[d];
    }
    y[j] = a * sigm(a);
  }
  bf16x8 o;
  if (g < 128) {                 // q (g<64) or k: l2norm over 64-ch head = 8 lanes
    float ss = 0.f;
#pragma unroll
    for (int j = 0; j < 8; ++j) ss += y[j] * y[j];
    ss += __shfl_xor(ss, 1);
    ss += __shfl_xor(ss, 2);
    ss += __shfl_xor(ss, 4);
    float sc = rsqrtf(ss + 1e-6f);
    if (g < 64) sc *= 0.125f;    // q additionally scaled DK^-0.5
#pragma unroll
    for (int j = 0; j < 8; ++j) ((u16*)&o)[j] = f2bf(y[j] * sc);
    if (g < 64) *(bf16x8*)(qn + (long)bt * 512 + c) = o;
    else        *(bf16x8*)(kn + (long)bt * 512 + (c - 512)) = o;
  } else {                       // v
#pragma unroll
    for (int j = 0; j < 8; ++j) ((u16*)&o)[j] = f2bf(y[j]);
    *(bf16x8*)(vb + (long)bt * 1024 + (c - 1024)) = o;
  }
  if (g < 16) {
    float xb = ba[(long)bt * 128 + g];
    beta[bt * 16 + g] = sigm(xb);
    float xa = ba[(long)bt * 128 + 16 + g] + dtb[g];
    float sp = (xa > 20.f) ? xa : log1pf(__expf(xa));
    gb[bt * 16 + g] = -__expf(Alog[g]) * sp;
  }
}

// ---------------- chunk-parallel (MFMA): A, blocked solve, P, B, M(row-major), G ----
__global__ __launch_bounds__(256) void k_cpk2(const u16* __restrict__ qn,
                                              const u16* __restrict__ kn,
                                              const u16* __restrict__ vb,
                                              const float* __restrict__ beta,
                                              const float* __restrict__ gb,
                                              float* __restrict__ Gbuf,
                                              u16* __restrict__ TKb,
                                              u16* __restrict__ WlTb, u16* __restrict__ Mb,
                                              u16* __restrict__ Pb, u16* __restrict__ Bb) {
  int c = blockIdx.x, hv = blockIdx.y, b = blockIdx.z;
  int hk = hv >> 1;
  int bh = b * HV_ + hv;
  int tid = threadIdx.x;
  int wv = tid >> 6, lane = tid & 63;
  int frow = lane & 15, fk = (lane >> 4) * 8;

  __shared__ __align__(16) char smem[78848];
  u16* Ks   = (u16*)smem;                  // [64][72]
  u16* Qs   = (u16*)(smem + 9216);         // [64][72], later Ktt
  u16* Ktt  = Qs;
  u16* As_  = (u16*)(smem + 18432);        // [64][72]
  u16* RHSt = (u16*)(smem + 27648);        // [128][72]
  u16* Xt   = (u16*)(smem + 46080);        // [128][72]
  u16* T4   = (u16*)(smem + 64512);        // [64][32]
  u16* Yl   = (u16*)(smem + 68608);        // [128][40]
  __shared__ float Gl[64];
  __shared__ float Bl[64];

  long tbase = (long)b * T_ + c * 64;
  long tile = ((long)bh * NC_ + c) * 4096;

  if (tid < 64) {
    Gl[tid] = gb[(tbase + tid) * HV_ + hv];
    Bl[tid] = beta[(tbase + tid) * HV_ + hv];
  }
  if (tid == 0) {
    float s = 0.f;
    for (int i = 0; i < 64; ++i) { s += Gl[i]; Gl[i] = s; }
  }
  if (tid < 64) Gbuf[((long)bh * NC_ + c) * 64 + tid] = Gl[tid];
  for (int e = tid; e < 4608; e += 256) ((float*)Xt)[e] = 0.f;
  for (int e = tid; e < 2560; e += 256) ((float*)Yl)[e] = 0.f;
  for (int e = tid; e < 4096; e += 256) {
    int i = e >> 6, k = e & 63;
    Ks[i * 72 + k] = kn[(tbase + i) * 512 + hk * 64 + k];
    Qs[i * 72 + k] = qn[(tbase + i) * 512 + hk * 64 + k];
  }
  __syncthreads();

  // M = Q@K^T (row-major out), A = K@K^T
  {
    bf16x8 aKs[2], aQs[2];
#pragma unroll
    for (int ks = 0; ks < 2; ++ks) {
      aKs[ks] = *(const bf16x8*)&Ks[(wv * 16 + frow) * 72 + ks * 32 + fk];
      aQs[ks] = *(const bf16x8*)&Qs[(wv * 16 + frow) * 72 + ks * 32 + fk];
    }
    f32x4 accM[4], accA[4];
#pragma unroll
    for (int nt = 0; nt < 4; ++nt) { accM[nt] = (f32x4){0,0,0,0}; accA[nt] = (f32x4){0,0,0,0}; }
#pragma unroll
    for (int ks = 0; ks < 2; ++ks) {
#pragma unroll
      for (int nt = 0; nt < 4; ++nt) {
        bf16x8 bk = *(const bf16x8*)&Ks[(nt * 16 + frow) * 72 + ks * 32 + fk];
        accM[nt] = __builtin_amdgcn_mfma_f32_16x16x32_bf16(aQs[ks], bk, accM[nt], 0, 0, 0);
        accA[nt] = __builtin_amdgcn_mfma_f32_16x16x32_bf16(aKs[ks], bk, accA[nt], 0, 0, 0);
      }
    }
    // M[i][s]: i = A-row(Q) -> C-row, s = B-row(K) -> C-col; keep s<=i
#pragma unroll
    for (int nt = 0; nt < 4; ++nt) {
      int s = nt * 16 + frow;
#pragma unroll
      for (int r = 0; r < 4; ++r) {
        int i = wv * 16 + (lane >> 4) * 4 + r;
        float val = (s <= i) ? accM[nt][r] * __expf(Gl[i] - Gl[s]) : 0.f;
        Mb[tile + i * 64 + s] = f2bf(val);
      }
    }
    // A[i][s]: strict lower, scale Bl[i]*exp(Gi-Gs)
#pragma unroll
    for (int nt = 0; nt < 4; ++nt) {
      int s = nt * 16 + frow;
#pragma unroll
      for (int r = 0; r < 4; ++r) {
        int i = wv * 16 + (lane >> 4) * 4 + r;
        float val = (s < i) ? Bl[i] * __expf(Gl[i] - Gl[s]) * accA[nt][r] : 0.f;
        As_[i * 72 + s] = f2bf(val);
      }
    }
  }

  for (int e = tid; e < 4096; e += 256) {
    int i = e >> 6, v = e & 63;
    RHSt[v * 72 + i] = f2bf(Bl[i] * bf2f(vb[(tbase + i) * 1024 + hv * 64 + v]));
  }
  for (int e = tid; e < 4096; e += 256) {
    int i = e >> 6, k = e & 63;
    RHSt[(64 + k) * 72 + i] = f2bf(Bl[i] * __expf(Gl[i]) * bf2f(Ks[i * 72 + k]));
  }
  __syncthreads();

  {
    if (lane < 16) {
      int cc = lane;
      float Tc[16];
#pragma unroll
      for (int j = 0; j < 16; ++j) Tc[j] = (j == cc) ? 1.f : 0.f;
#pragma unroll
      for (int s = 0; s < 15; ++s)
#pragma unroll
        for (int i = s + 1; i < 16; ++i) {
          float a = bf2f(As_[(wv * 16 + i) * 72 + wv * 16 + s]);
          Tc[i] -= a * Tc[s];
        }
#pragma unroll
      for (int i = 0; i < 16; ++i) T4[(wv * 16 + i) * 32 + cc] = f2bf(Tc[i]);
    } else if (lane < 32) {
      int c2 = lane - 16;
#pragma unroll
      for (int i = 0; i < 16; ++i) T4[(wv * 16 + i) * 32 + 16 + c2] = 0;
    }
  }
  __syncthreads();

#pragma unroll 1
  for (int bb = 0; bb < 4; ++bb) {
    f32x4 uacc[2];
    uacc[0] = (f32x4){0,0,0,0}; uacc[1] = (f32x4){0,0,0,0};
#pragma unroll
    for (int ks = 0; ks < 2; ++ks) {
      bf16x8 bfr = *(const bf16x8*)&As_[(bb * 16 + frow) * 72 + ks * 32 + fk];
#pragma unroll
      for (int mt = 0; mt < 2; ++mt) {
        bf16x8 aa = *(const bf16x8*)&Xt[((wv * 2 + mt) * 16 + frow) * 72 + ks * 32 + fk];
        uacc[mt] = __builtin_amdgcn_mfma_f32_16x16x32_bf16(aa, bfr, uacc[mt], 0, 0, 0);
      }
    }
#pragma unroll
    for (int mt = 0; mt < 2; ++mt)
#pragma unroll
      for (int r = 0; r < 4; ++r) {
        int vr = (wv * 2 + mt) * 16 + (lane >> 4) * 4 + r;
        float y = bf2f(RHSt[vr * 72 + bb * 16 + frow]) - uacc[mt][r];
        Yl[vr * 40 + frow] = f2bf(y);
      }
    __syncthreads();
    {
      bf16x8 tb = *(const bf16x8*)&T4[(bb * 16 + frow) * 32 + fk];
      f32x4 zacc[2];
      zacc[0] = (f32x4){0,0,0,0}; zacc[1] = (f32x4){0,0,0,0};
#pragma unroll
      for (int mt = 0; mt < 2; ++mt) {
        bf16x8 aa = *(const bf16x8*)&Yl[((wv * 2 + mt) * 16 + frow) * 40 + fk];
        zacc[mt] = __builtin_amdgcn_mfma_f32_16x16x32_bf16(aa, tb, zacc[mt], 0, 0, 0);
      }
#pragma unroll
      for (int mt = 0; mt < 2; ++mt)
#pragma unroll
        for (int r = 0; r < 4; ++r) {
          int vr = (wv * 2 + mt) * 16 + (lane >> 4) * 4 + r;
          Xt[vr * 72 + bb * 16 + frow] = f2bf(zacc[mt][r]);
        }
    }
    __syncthreads();
  }

  float gend = Gl[63];
  for (int e = tid; e < 4096; e += 256) {
    int i = e >> 6, r = e & 63;
    Ktt[r * 72 + i] = f2bf(__expf(gend - Gl[i]) * bf2f(Ks[i * 72 + r]));
  }
  // WlT rows (0..63) row copy; TK row-major via transposed copy
#pragma unroll
  for (int t8 = 0; t8 < 1; ++t8) {
    int seg = tid;                     // 0..255
    int row = seg >> 2, s4 = (seg & 3) * 16;
    bf16x8 x0 = *(const bf16x8*)&Xt[row * 72 + s4];
    bf16x8 x1 = *(const bf16x8*)&Xt[row * 72 + s4 + 8];
    *(bf16x8*)(WlTb + tile + row * 64 + s4) = x0;
    *(bf16x8*)(WlTb + tile + row * 64 + s4 + 8) = x1;
  }
  for (int e = tid; e < 4096; e += 256) {
    int i = e >> 6, k = e & 63;
    TKb[tile + e] = Xt[(64 + k) * 72 + i];
  }
  __syncthreads();

  // B[r][v] = Ktt @ Wl-part of Xt
  {
    f32x4 acc[4];
#pragma unroll
    for (int nt = 0; nt < 4; ++nt) acc[nt] = (f32x4){0,0,0,0};
#pragma unroll
    for (int ks = 0; ks < 2; ++ks) {
      bf16x8 aa = *(const bf16x8*)&Ktt[(wv * 16 + frow) * 72 + ks * 32 + fk];
#pragma unroll
      for (int nt = 0; nt < 4; ++nt) {
        bf16x8 bfr = *(const bf16x8*)&Xt[(nt * 16 + frow) * 72 + ks * 32 + fk];
        acc[nt] = __builtin_amdgcn_mfma_f32_16x16x32_bf16(aa, bfr, acc[nt], 0, 0, 0);
      }
    }
#pragma unroll
    for (int nt = 0; nt < 4; ++nt) {
      int v = nt * 16 + frow;
#pragma unroll
      for (int r = 0; r < 4; ++r) {
        int rr = wv * 16 + (lane >> 4) * 4 + r;
        Bb[tile + rr * 64 + v] = f2bf(acc[nt][r]);
      }
    }
  }
  // P^T[k2][r] = TK^T-part of Xt @ Ktt^T
  {
    f32x4 acc[4];
#pragma unroll
    for (int nt = 0; nt < 4; ++nt) acc[nt] = (f32x4){0,0,0,0};
#pragma unroll
    for (int ks = 0; ks < 2; ++ks) {
      bf16x8 aa = *(const bf16x8*)&Xt[(64 + wv * 16 + frow) * 72 + ks * 32 + fk];
#pragma unroll
      for (int nt = 0; nt < 4; ++nt) {
        bf16x8 bfr = *(const bf16x8*)&Ktt[(nt * 16 + frow) * 72 + ks * 32 + fk];
        acc[nt] = __builtin_amdgcn_mfma_f32_16x16x32_bf16(aa, bfr, acc[nt], 0, 0, 0);
      }
    }
#pragma unroll
    for (int nt = 0; nt < 4; ++nt) {
      int rr = nt * 16 + frow;
#pragma unroll
      for (int r = 0; r < 4; ++r) {
        int k2 = wv * 16 + (lane >> 4) * 4 + r;
        Pb[tile + k2 * 64 + rr] = f2bf(acc[nt][r]);
      }
    }
  }
}

// ---------------- serial scan over chunks: S' = g*S - P@S + B ----------------
__global__ __launch_bounds__(256) void k_seq2(const u16* __restrict__ Pb,
                                              const u16* __restrict__ Bb,
                                              const float* __restrict__ Gbuf,
                                              u16* __restrict__ Stb) {
  int vblk = blockIdx.x, bh = blockIdx.y;
  int tid = threadIdx.x;
  __shared__ u16 Abf[2][4096];
  __shared__ u16 Bbf[2][512];
  __shared__ float S_lds[64][10];
  __shared__ float gam[NC_];
  int i_ = tid & 63, vg = tid >> 6;
  int wv = tid >> 6, ln = tid & 63;
  if (tid < NC_) gam[tid] = __expf(Gbuf[((long)bh * NC_ + tid) * 64 + 63]);
  for (int e = tid; e < 640; e += 256) ((float*)S_lds)[e] = 0.f;
  float a0 = 0.f, a1 = 0.f;
  {
    long tl = (long)bh * NC_ * 4096;
    const u16* gA = Pb + tl + wv * 512 + ln * 8;
    __builtin_amdgcn_global_load_lds((gptr_t)gA, (lptr_t)&Abf[0][wv * 512], 16, 0, 0);
    __builtin_amdgcn_global_load_lds((gptr_t)(gA + 2048), (lptr_t)&Abf[0][2048 + wv * 512], 16, 0, 0);
    int ii = tid >> 2, vp = tid & 3;
    const u16* gB = Bb + tl + ii * 64 + vblk * 8 + vp * 2;
    __builtin_amdgcn_global_load_lds((gptr_t)gB, (lptr_t)&Bbf[0][wv * 128], 4, 0, 0);
  }
  for (int c = 0; c < NC_; ++c) {
    int cur = c & 1;
    asm volatile("s_waitcnt vmcnt(0)" ::: "memory");
    __syncthreads();
    if (c + 1 < NC_) {
      long tl = ((long)bh * NC_ + c + 1) * 4096;
      const u16* gA = Pb + tl + wv * 512 + ln * 8;
      __builtin_amdgcn_global_load_lds((gptr_t)gA, (lptr_t)&Abf[cur ^ 1][wv * 512], 16, 0, 0);
      __builtin_amdgcn_global_load_lds((gptr_t)(gA + 2048), (lptr_t)&Abf[cur ^ 1][2048 + wv * 512], 16, 0, 0);
      int ii = tid >> 2, vp = tid & 3;
      const u16* gB = Bb + tl + ii * 64 + vblk * 8 + vp * 2;
      __builtin_amdgcn_global_load_lds((gptr_t)gB, (lptr_t)&Bbf[cur ^ 1][wv * 128], 4, 0, 0);
    }
    {
      long stile = ((long)bh * NC_ + c) * 4096;
      int v0 = vblk * 8 + vg * 2;
      Stb[stile + (long)v0 * 64 + i_] = f2bf(a0);
      Stb[stile + (long)(v0 + 1) * 64 + i_] = f2bf(a1);
    }
    float g = gam[c];
    float n0 = 0.f, n1 = 0.f;
#pragma unroll 8
    for (int k = 0; k < 64; ++k) {
      float p = bf2f(Abf[cur][k * 64 + i_]);
      float2 sv = *(const float2*)&S_lds[k][vg * 2];
      n0 += p * sv.x;
      n1 += p * sv.y;
    }
    float b0 = bf2f(Bbf[cur][i_ * 8 + vg * 2]);
    float b1 = bf2f(Bbf[cur][i_ * 8 + vg * 2 + 1]);
    a0 = g * a0 - n0 + b0;
    a1 = g * a1 - n1 + b1;
    __syncthreads();
    S_lds[i_][vg * 2] = a0;
    S_lds[i_][vg * 2 + 1] = a1;
  }
}

// ---------------- outputs (MFMA): Wt = Wl^T - (TK@S)^T;  O = M@W + Qh@S ----------
__global__ __launch_bounds__(256) void k_ok3(const u16* __restrict__ Mb,
                                             const u16* __restrict__ TKb,
                                             const u16* __restrict__ WlTb,
                                             const u16* __restrict__ Stb,
                                             const u16* __restrict__ qn,
                                             const float* __restrict__ Gbuf,
                                             float* __restrict__ O) {
  int c = blockIdx.x, hv = blockIdx.y, b = blockIdx.z;
  int bh = b * HV_ + hv, hk = hv >> 1;
  int tid = threadIdx.x;
  int wv = tid >> 6, lane = tid & 63;
  int frow = lane & 15, fk = (lane >> 4) * 8;
  __shared__ __align__(16) u16 St[64 * 72];    // S^T[v][k]
  __shared__ __align__(16) u16 TKr[64 * 72];   // TK[i][k]; reused as M[i][s]
  __shared__ __align__(16) u16 Wl_[64 * 72];   // Wl^T[v][i] -> Wt[v][s]
  __shared__ __align__(16) u16 Qh[64 * 72];    // exp(Gi)*Q[i][k]
  __shared__ float Gl[64];
  long tile = ((long)bh * NC_ + c) * 4096;
  long tbase = (long)b * T_ + c * 64;
  if (tid < 64) Gl[tid] = Gbuf[((long)bh * NC_ + c) * 64 + tid];
  // prefetch M tile to regs (written to LDS after phase A)
  bf16x8 mreg[2];
#pragma unroll
  for (int j = 0; j < 2; ++j) mreg[j] = *(const bf16x8*)(Mb + tile + tid * 16 + j * 8);
  __syncthreads();
  for (int e = tid; e < 4096; e += 256) {
    int r = e >> 6, x = e & 63;
    St[r * 72 + x] = Stb[tile + e];
    TKr[r * 72 + x] = TKb[tile + e];
    Wl_[r * 72 + x] = WlTb[tile + e];
    Qh[r * 72 + x] = f2bf(__expf(Gl[r]) * bf2f(qn[(tbase + r) * 512 + hk * 64 + x]));
  }
  __syncthreads();
  // phase A: D1[v][i] = sum_k St[v][k]*TK[i][k];  Wt[v][i] = Wl^T - D1 (in-place)
  {
    f32x4 acc1[4];
#pragma unroll
    for (int nt = 0; nt < 4; ++nt) acc1[nt] = (f32x4){0,0,0,0};
#pragma unroll
    for (int ks = 0; ks < 2; ++ks) {
      bf16x8 aa = *(const bf16x8*)&St[(wv * 16 + frow) * 72 + ks * 32 + fk];
#pragma unroll
      for (int nt = 0; nt < 4; ++nt) {
        bf16x8 bb2 = *(const bf16x8*)&TKr[(nt * 16 + frow) * 72 + ks * 32 + fk];
        acc1[nt] = __builtin_amdgcn_mfma_f32_16x16x32_bf16(aa, bb2, acc1[nt], 0, 0, 0);
      }
    }
#pragma unroll
    for (int nt = 0; nt < 4; ++nt) {
      int i = nt * 16 + frow;
#pragma unroll
      for (int r = 0; r < 4; ++r) {
        int v = wv * 16 + (lane >> 4) * 4 + r;
        float wt = bf2f(Wl_[v * 72 + i]) - acc1[nt][r];
        Wl_[v * 72 + i] = f2bf(wt);
      }
    }
  }
  __syncthreads();
  // M into TKr space
#pragma unroll
  for (int j = 0; j < 2; ++j) {
    int e = tid * 16 + j * 8;
    *(bf16x8*)&TKr[(e >> 6) * 72 + (e & 63)] = mreg[j];
  }
  __syncthreads();
  // phase B: O[i][v] = sum_s M[i][s]*Wt[v][s] + sum_k Qh[i][k]*St[v][k]
  {
    f32x4 acc2[4];
#pragma unroll
    for (int nt = 0; nt < 4; ++nt) acc2[nt] = (f32x4){0,0,0,0};
#pragma unroll
    for (int ks = 0; ks < 2; ++ks) {
      bf16x8 am = *(const bf16x8*)&TKr[(wv * 16 + frow) * 72 + ks * 32 + fk];
      bf16x8 aq = *(const bf16x8*)&Qh[(wv * 16 + frow) * 72 + ks * 32 + fk];
#pragma unroll
      for (int nt = 0; nt < 4; ++nt) {
        bf16x8 bw = *(const bf16x8*)&Wl_[(nt * 16 + frow) * 72 + ks * 32 + fk];
        bf16x8 bs = *(const bf16x8*)&St[(nt * 16 + frow) * 72 + ks * 32 + fk];
        acc2[nt] = __builtin_amdgcn_mfma_f32_16x16x32_bf16(am, bw, acc2[nt], 0, 0, 0);
        acc2[nt] = __builtin_amdgcn_mfma_f32_16x16x32_bf16(aq, bs, acc2[nt], 0, 0, 0);
      }
    }
#pragma unroll
    for (int nt = 0; nt < 4; ++nt) {
      int v = nt * 16 + frow;
#pragma unroll
      for (int r = 0; r < 4; ++r) {
        int i = wv * 16 + (lane >> 4) * 4 + r;
        O[((tbase + i) * HV_ + hv) * 64 + v] = acc2[nt][r];
      }
    }
  }
}

// ---------------- gated RMSNorm ----------------
__global__ __launch_bounds__(256) void k_rms(const float* __restrict__ O,
                                             const u16* __restrict__ qkvz,
                                             const float* __restrict__ normw,
                                             u16* __restrict__ on) {
  int bt = blockIdx.x;
  int tid = threadIdx.x;
  __shared__ float ps[256];
  __shared__ float rstd[16];
  float4 o4 = *(const float4*)&O[(long)bt * 1024 + tid * 4];
  ps[tid] = o4.x * o4.x + o4.y * o4.y + o4.z * o4.z + o4.w * o4.w;
  __syncthreads();
  if (tid < 16) {
    float s = 0.f;
#pragma unroll
    for (int u = 0; u < 16; ++u) s += ps[tid * 16 + u];
    rstd[tid] = rsqrtf(s * (1.f / 64.f) + 1e-6f);
  }
  __syncthreads();
  float rs = rstd[tid >> 4];
  u16x4 ov;
#pragma unroll
  for (int j = 0; j < 4; ++j) {
    int idx = tid * 4 + j;
    float z = bf2f(qkvz[(long)bt * QKVZ_ + 2048 + idx]);
    float val = ((const float*)&o4)[j] * rs * normw[idx & 63] * (z * sigm(z));
    ((u16*)&ov)[j] = f2bf(val);
  }
  *(u16x4*)(on + (long)bt * 1024 + tid * 4) = ov;
}

// ---------------- host launch ----------------
extern "C" void kernel_launch(void* const* d_in, const int* in_sizes, int n_in,
                              void* d_out, int out_size, void* d_ws, size_t ws_size,
                              hipStream_t stream) {
  const float* hs    = (const float*)d_in[0];
  const float* Wqkv  = (const float*)d_in[1];
  const float* Wz    = (const float*)d_in[2];
  const float* Wb    = (const float*)d_in[3];
  const float* Wa    = (const float*)d_in[4];
  const float* dtb   = (const float*)d_in[5];
  const float* Alog  = (const float*)d_in[6];
  const float* convw = (const float*)d_in[7];
  const float* normw = (const float*)d_in[8];
  const float* Wout  = (const float*)d_in[9];
  float* out = (float*)d_out;

  char* p = (char*)d_ws;
  auto take = [&](size_t bytes) {
    char* q = p;
    p += (bytes + 255) & ~(size_t)255;
    return (void*)q;
  };
  u16*   qkvz  = (u16*)take((size_t)BT_ * QKVZ_ * 2);
  float* ba    = (float*)take((size_t)BT_ * 128 * 4);
  u16*   hsb   = (u16*)take((size_t)BT_ * 1024 * 2);
  u16*   wcatT = (u16*)take((size_t)NPAD_ * 1024 * 2);
  u16*   woutT = (u16*)take((size_t)1024 * 1024 * 2);
  u16*   qn    = (u16*)take((size_t)BT_ * 512 * 2);
  u16*   kn    = (u16*)take((size_t)BT_ * 512 * 2);
  u16*   vbuf  = (u16*)take((size_t)BT_ * 1024 * 2);
  float* beta  = (float*)take((size_t)BT_ * 16 * 4);
  float* gbuf  = (float*)take((size_t)BT_ * 16 * 4);
  float* Gcum  = (float*)take((size_t)1024 * 64 * 4);
  u16*   TKb   = (u16*)take((size_t)1024 * 4096 * 2);
  u16*   WlTb  = (u16*)take((size_t)1024 * 4096 * 2);
  u16*   Mb    = (u16*)take((size_t)1024 * 4096 * 2);
  u16*   Pb    = (u16*)take((size_t)1024 * 4096 * 2);
  u16*   Bb    = (u16*)take((size_t)1024 * 4096 * 2);
  u16*   Stb   = (u16*)take((size_t)1024 * 4096 * 2);
  float* Obuf  = (float*)take((size_t)BT_ * 1024 * 4);
  u16*   onb   = (u16*)take((size_t)BT_ * 1024 * 2);

  k_cast_hs<<<dim3(4096), dim3(256), 0, stream>>>(hs, hsb);
  k_wcatT<<<dim3(104, 32), dim3(256), 0, stream>>>(Wqkv, Wz, Wb, Wa, wcatT);
  k_tcast<<<dim3(32, 32), dim3(256), 0, stream>>>(Wout, woutT, 1024, 1024);
  k_g1<<<dim3(13, 16), dim3(512), 131072, stream>>>(hsb, wcatT, qkvz, ba);
  k_conv<<<dim3(4096), dim3(256), 0, stream>>>(qkvz, ba, convw, Alog, dtb, qn, kn, vbuf, beta, gbuf);
  k_cpk2<<<dim3(32, 16, 2), dim3(256), 0, stream>>>(qn, kn, vbuf, beta, gbuf, Gcum, TKb, WlTb, Mb, Pb, Bb);
  k_seq2<<<dim3(8, 32), dim3(256), 0, stream>>>(Pb, Bb, Gcum, Stb);
  k_ok3<<<dim3(32, 16, 2), dim3(256), 0, stream>>>(Mb, TKb, WlTb, Stb, qn, Gcum, Obuf);
  k_rms<<<dim3(4096), dim3(256), 0, stream>>>(Obuf, qkvz, normw, onb);
  k_gemm<<<dim3(8, 32), dim3(256), 0, stream>>>(onb, woutT, out, 4096, 1024, 1024);
}